// Round 3
// baseline (3161.415 us; speedup 1.0000x reference)
//
#include <hip/hip_runtime.h>
#include <float.h>
#include <stdint.h>

#define D_DIM 512
#define MARGIN 0.1f   // = 2*e with e=0.05 >> true approx-score error bound (~3e-3)

typedef unsigned short ushort_t;
typedef unsigned int u32;
typedef __attribute__((ext_vector_type(8))) short short8v;     // 8 bf16 (4 VGPRs)
typedef __attribute__((ext_vector_type(8))) unsigned short ushort8v;
typedef __attribute__((ext_vector_type(4))) float f32x4;

__device__ __forceinline__ ushort_t f32_bf16_rne(float x) {
    u32 u = __float_as_uint(x);
    u32 r = (u + 0x7fffu + ((u >> 16) & 1u)) >> 16;
    return (ushort_t)r;
}
__device__ __forceinline__ float bf16_f32(ushort_t h) {
    return __uint_as_float(((u32)h) << 16);
}
__device__ __forceinline__ void gload_lds16(const void* g, void* l) {
    __builtin_amdgcn_global_load_lds(
        (const __attribute__((address_space(1))) u32*)(g),
        (__attribute__((address_space(3))) u32*)(l), 16, 0, 0);
}

// ============ prep: split z into bf16 hi/lo ================================
__global__ __launch_bounds__(256) void split_z_kernel(const float* __restrict__ z,
                                                      ushort_t* __restrict__ z_hi,
                                                      ushort_t* __restrict__ z_lo,
                                                      long total8) {
    long i = (long)blockIdx.x * 256 + threadIdx.x;
    if (i >= total8) return;
    const float4* p = (const float4*)(z + i * 8);
    float4 a = p[0], b = p[1];
    float x[8] = {a.x, a.y, a.z, a.w, b.x, b.y, b.z, b.w};
    ushort8v h, lo;
    #pragma unroll
    for (int j = 0; j < 8; ++j) {
        ushort_t hh = f32_bf16_rne(x[j]);
        h[j] = hh;
        lo[j] = f32_bf16_rne(x[j] - bf16_f32(hh));
    }
    *(ushort8v*)(z_hi + i * 8) = h;
    *(ushort8v*)(z_lo + i * 8) = lo;
}

// ============ prep: split codebook + norms (f32/f64) + zero freq ===========
__global__ __launch_bounds__(256) void split_cb_kernel(const float* __restrict__ cb,
                                                       ushort_t* __restrict__ cb_hi,
                                                       ushort_t* __restrict__ cb_lo,
                                                       float* __restrict__ csq32,
                                                       double* __restrict__ csq64,
                                                       float* __restrict__ freq,
                                                       int K) {
    int tid = threadIdx.x;
    int gt = blockIdx.x * 256 + tid;
    if (gt < K) freq[gt] = 0.0f;

    int wv = tid >> 6, lane = tid & 63;
    int k = blockIdx.x * 4 + wv;
    if (k >= K) return;
    const float* row = cb + (size_t)k * D_DIM;
    float4 a = *(const float4*)(row + lane * 8);
    float4 b = *(const float4*)(row + lane * 8 + 4);
    float x[8] = {a.x, a.y, a.z, a.w, b.x, b.y, b.z, b.w};
    ushort8v h, lo;
    double s = 0.0;
    #pragma unroll
    for (int j = 0; j < 8; ++j) {
        s += (double)x[j] * x[j];
        ushort_t hh = f32_bf16_rne(x[j]);
        h[j] = hh;
        lo[j] = f32_bf16_rne(x[j] - bf16_f32(hh));
    }
    *(ushort8v*)(cb_hi + (size_t)k * D_DIM + lane * 8) = h;
    *(ushort8v*)(cb_lo + (size_t)k * D_DIM + lane * 8) = lo;
    #pragma unroll
    for (int off = 32; off > 0; off >>= 1) s += __shfl_down(s, off);
    if (lane == 0) { csq64[k] = s; csq32[k] = (float)s; }
}

// ============ pass 1: split-bf16 MFMA GEMM + per-row candidates ============
// Block: 256 thr = 4 waves (2x2), wave tile 64x64, block tile 128 rows x 128 codes.
// In-kernel loop over 32 code tiles; virtual-K = 3 segments x 512 (hi*hi, hi*lo, lo*hi).
// LDS 64KB: A dbuf 2x16KB + B dbuf 2x16KB. XOR-swizzle (slot ^= row&7) applied by
// pre-swizzling the global source (gload_lds writes linearly) and on ds_read.
__global__ __launch_bounds__(256, 2) void pass1_mfma_kernel(
        const ushort_t* __restrict__ z_hi, const ushort_t* __restrict__ z_lo,
        const ushort_t* __restrict__ cb_hi, const ushort_t* __restrict__ cb_lo,
        const float* __restrict__ csq32,
        int* __restrict__ cand_cnt, int* __restrict__ cand_k, int K) {
    extern __shared__ char smem[];
    const int tid = threadIdx.x;
    const int wid = tid >> 6;
    const int lane = tid & 63;
    const int wm = wid >> 1, wn = wid & 1;
    const int c = lane & 15, g = lane >> 4;
    const int row0 = blockIdx.x * 128;

    f32x4 acc[4][4];
    float tv0[16], tv1[16]; int tk0[16], tk1[16];
    #pragma unroll
    for (int i = 0; i < 16; ++i) { tv0[i] = FLT_MAX; tv1[i] = FLT_MAX; tk0[i] = 0; tk1[i] = 0; }

    auto STAGE = [&](int buf, int ct_, int t_) {
        int seg = t_ >> 3;                 // 0: hi*hi, 1: hi*lo, 2: lo*hi
        int dtt = (t_ & 7) << 6;           // d-offset within segment
        const ushort_t* As = (seg == 2) ? z_lo : z_hi;
        const ushort_t* Bs = (seg == 1) ? cb_lo : cb_hi;
        int code0_ = ct_ << 7;
        #pragma unroll
        for (int r = 0; r < 4; ++r) {
            int s = r * 256 + tid;         // 16B slot id 0..1023
            int rw = s >> 3, p = s & 7;    // row 0..127, slot-in-row 0..7
            int dswz = dtt + ((p ^ (rw & 7)) << 3);   // pre-swizzled source
            gload_lds16(As + (size_t)(row0 + rw) * D_DIM + dswz,
                        smem + buf * 16384 + r * 4096 + wid * 1024);
            gload_lds16(Bs + (size_t)(code0_ + rw) * D_DIM + dswz,
                        smem + 32768 + buf * 16384 + r * 4096 + wid * 1024);
        }
    };

    auto COMPUTE = [&](int buf) {
        const char* Ab = smem + buf * 16384;
        const char* Bb = smem + 32768 + buf * 16384;
        #pragma unroll
        for (int ks = 0; ks < 2; ++ks) {
            int q = ks * 4 + g;            // logical 16B k-slot
            short8v a[4], b[4];
            #pragma unroll
            for (int fm = 0; fm < 4; ++fm) {
                int rl = wm * 64 + fm * 16 + c;
                a[fm] = *(const short8v*)(Ab + rl * 128 + ((q ^ (rl & 7)) << 4));
            }
            #pragma unroll
            for (int fn = 0; fn < 4; ++fn) {
                int cl = wn * 64 + fn * 16 + c;
                b[fn] = *(const short8v*)(Bb + cl * 128 + ((q ^ (cl & 7)) << 4));
            }
            #pragma unroll
            for (int fm = 0; fm < 4; ++fm)
                #pragma unroll
                for (int fn = 0; fn < 4; ++fn)
                    acc[fm][fn] = __builtin_amdgcn_mfma_f32_16x16x32_bf16(
                        a[fm], b[fn], acc[fm][fn], 0, 0, 0);
        }
    };

    STAGE(0, 0, 0);
    for (int ct = 0; ct < 32; ++ct) {
        f32x4 zz = {0.f, 0.f, 0.f, 0.f};
        #pragma unroll
        for (int fm = 0; fm < 4; ++fm)
            #pragma unroll
            for (int fn = 0; fn < 4; ++fn) acc[fm][fn] = zz;

        for (int t = 0; t < 24; ++t) {
            __syncthreads();               // stage(t) complete (vmcnt0 + barrier)
            if (t < 23)       STAGE((t + 1) & 1, ct, t + 1);
            else if (ct < 31) STAGE(0, ct + 1, 0);   // 24 even -> next ct starts buf0
            COMPUTE(t & 1);
        }

        // epilogue: scores + per-(thread,row) top-2 (registers only, no LDS)
        int code0 = ct << 7;
        float cq[4];
        #pragma unroll
        for (int fn = 0; fn < 4; ++fn) cq[fn] = csq32[code0 + wn * 64 + fn * 16 + c];
        #pragma unroll
        for (int fm = 0; fm < 4; ++fm)
            #pragma unroll
            for (int fn = 0; fn < 4; ++fn) {
                int code = code0 + wn * 64 + fn * 16 + c;
                #pragma unroll
                for (int rg = 0; rg < 4; ++rg) {
                    float sv = fmaf(-2.0f, acc[fm][fn][rg], cq[fn]);
                    int rp = fm * 4 + rg;
                    if (sv < tv1[rp]) {
                        if (sv < tv0[rp]) {
                            tv1[rp] = tv0[rp]; tk1[rp] = tk0[rp];
                            tv0[rp] = sv;      tk0[rp] = code;
                        } else { tv1[rp] = sv; tk1[rp] = code; }
                    }
                }
            }
    }

    // ---- merge 64 candidates/row (32 threads x top-2), prove coverage ----
    __syncthreads();                       // all compute done; staging LDS reusable
    float* mv = (float*)smem;              // [128][64]
    int*   mi = (int*)(smem + 32768);      // [128][64]
    #pragma unroll
    for (int fm = 0; fm < 4; ++fm)
        #pragma unroll
        for (int rg = 0; rg < 4; ++rg) {
            int rl = wm * 64 + fm * 16 + g * 4 + rg;   // C row mapping
            int slot = wn * 16 + c;
            int rp = fm * 4 + rg;
            mv[rl * 64 + slot * 2]     = tv0[rp];
            mv[rl * 64 + slot * 2 + 1] = tv1[rp];
            mi[rl * 64 + slot * 2]     = tk0[rp];
            mi[rl * 64 + slot * 2 + 1] = tk1[rp];
        }
    __syncthreads();
    if (tid < 128) {
        const float* rv = mv + tid * 64;
        const int*   ri = mi + tid * 64;
        float v0 = FLT_MAX, w = FLT_MAX;
        for (int j = 0; j < 64; ++j) v0 = fminf(v0, rv[j]);
        for (int j = 1; j < 64; j += 2) w = fminf(w, rv[j]);  // min of lane-seconds
        float lim = v0 + MARGIN;
        int cnt = 0; int ks[8];
        for (int j = 0; j < 64; ++j)
            if (rv[j] <= lim) { if (cnt < 8) ks[cnt] = ri[j]; cnt++; }
        // coverage proof: every non-candidate code scores >= its slot's 2nd >= w
        bool ok = (w - v0 >= MARGIN) && (cnt >= 1) && (cnt <= 8);
        int gr = row0 + tid;
        if (!ok) cand_cnt[gr] = 0;         // rare: full f64 scan in pass 2
        else {
            cand_cnt[gr] = cnt;
            for (int m = 0; m < cnt; ++m) cand_k[gr * 8 + m] = ks[m];
        }
    }
}

// ============ pass 2: f64 rescore of filtered candidates + outputs =========
__global__ __launch_bounds__(256) void pass2_new_kernel(
        const float* __restrict__ z, const float* __restrict__ cb,
        const double* __restrict__ csq64,
        const int* __restrict__ cand_cnt, const int* __restrict__ cand_k,
        float* __restrict__ zq, float* __restrict__ oidx, float* __restrict__ freq,
        int N, int K) {
    int lane = threadIdx.x & 63;
    int row = blockIdx.x * 4 + (threadIdx.x >> 6);
    if (row >= N) return;

    int cnt = cand_cnt[row];
    int best_k;
    if (cnt == 1) {
        best_k = cand_k[(size_t)row * 8];
    } else {
        const float* zrow = z + (size_t)row * D_DIM;
        float4 z0 = *(const float4*)(zrow + lane * 4);
        float4 z1 = *(const float4*)(zrow + 256 + lane * 4);
        double best_s = DBL_MAX; int bk = 0x7fffffff;
        if (cnt >= 2) {
            for (int m = 0; m < cnt; ++m) {
                int k = cand_k[(size_t)row * 8 + m];
                const float* crow = cb + (size_t)k * D_DIM;
                float4 c0 = *(const float4*)(crow + lane * 4);
                float4 c1 = *(const float4*)(crow + 256 + lane * 4);
                double a = (double)z0.x * c0.x + (double)z0.y * c0.y +
                           (double)z0.z * c0.z + (double)z0.w * c0.w +
                           (double)z1.x * c1.x + (double)z1.y * c1.y +
                           (double)z1.z * c1.z + (double)z1.w * c1.w;
                #pragma unroll
                for (int off = 32; off > 0; off >>= 1) a += __shfl_down(a, off);
                if (lane == 0) {
                    double s = csq64[k] - 2.0 * a;
                    if (s < best_s || (s == best_s && k < bk)) { best_s = s; bk = k; }
                }
            }
        } else {
            for (int k = 0; k < K; ++k) {
                const float* crow = cb + (size_t)k * D_DIM;
                float4 c0 = *(const float4*)(crow + lane * 4);
                float4 c1 = *(const float4*)(crow + 256 + lane * 4);
                double a = (double)z0.x * c0.x + (double)z0.y * c0.y +
                           (double)z0.z * c0.z + (double)z0.w * c0.w +
                           (double)z1.x * c1.x + (double)z1.y * c1.y +
                           (double)z1.z * c1.z + (double)z1.w * c1.w;
                #pragma unroll
                for (int off = 32; off > 0; off >>= 1) a += __shfl_down(a, off);
                if (lane == 0) {
                    double s = csq64[k] - 2.0 * a;
                    if (s < best_s) { best_s = s; bk = k; }
                }
            }
        }
        best_k = __shfl(bk, 0);
    }

    if (lane == 0) {
        oidx[row] = (float)best_k;
        atomicAdd(&freq[best_k], 1.0f);
    }
    const float* crow = cb + (size_t)best_k * D_DIM;
    *(float4*)(zq + (size_t)row * D_DIM + lane * 4) = *(const float4*)(crow + lane * 4);
    *(float4*)(zq + (size_t)row * D_DIM + 256 + lane * 4) = *(const float4*)(crow + 256 + lane * 4);
}

// ================= fallback path (R2-passing f32 pipeline) =================
__global__ __launch_bounds__(256) void csq_kernel(const float* __restrict__ cb,
                                                  float* __restrict__ csq32,
                                                  double* __restrict__ csq64,
                                                  float* __restrict__ freq,
                                                  int K) {
    int tid = threadIdx.x;
    int gt = blockIdx.x * 256 + tid;
    if (gt < K) freq[gt] = 0.0f;
    int wave = tid >> 6, lane = tid & 63;
    int k = blockIdx.x * 4 + wave;
    if (k >= K) return;
    const float* row = cb + (size_t)k * D_DIM;
    float4 v0 = *(const float4*)(row + lane * 4);
    float4 v1 = *(const float4*)(row + 256 + lane * 4);
    double s = (double)v0.x * v0.x + (double)v0.y * v0.y +
               (double)v0.z * v0.z + (double)v0.w * v0.w +
               (double)v1.x * v1.x + (double)v1.y * v1.y +
               (double)v1.z * v1.z + (double)v1.w * v1.w;
    #pragma unroll
    for (int off = 32; off > 0; off >>= 1) s += __shfl_down(s, off);
    if (lane == 0) { csq64[k] = s; csq32[k] = (float)s; }
}

__device__ __forceinline__ void top4_insert(float (&v)[4], int (&ki)[4], float s, int k) {
    if (s < v[3]) {
        v[3] = s; ki[3] = k;
        if (v[3] < v[2]) {
            float t = v[3]; v[3] = v[2]; v[2] = t; int u = ki[3]; ki[3] = ki[2]; ki[2] = u;
            if (v[2] < v[1]) {
                t = v[2]; v[2] = v[1]; v[1] = t; u = ki[2]; ki[2] = ki[1]; ki[1] = u;
                if (v[1] < v[0]) {
                    t = v[1]; v[1] = v[0]; v[0] = t; u = ki[1]; ki[1] = ki[0]; ki[0] = u;
                }
            }
        }
    }
}

#define BM 64
#define BK 128
#define BD 32
#define ZS_STRIDE (BM + 4)
#define CS_STRIDE (BK + 4)

__global__ __launch_bounds__(256) void pass1_kernel(const float* __restrict__ z,
                                                    const float* __restrict__ cb,
                                                    const float* __restrict__ csq32,
                                                    float* __restrict__ cand_v,
                                                    int* __restrict__ cand_i,
                                                    int K) {
    __shared__ float zs[BD][ZS_STRIDE];
    __shared__ float cs[BD][CS_STRIDE];
    __shared__ float mvv[BM][64];
    __shared__ int   mii[BM][64];
    const int tid = threadIdx.x;
    const int rg = tid & 15;
    const int cg = tid >> 4;
    const int row0 = blockIdx.x * BM;
    float tv[4][4]; int tk[4][4];
    #pragma unroll
    for (int r = 0; r < 4; ++r)
        #pragma unroll
        for (int m = 0; m < 4; ++m) { tv[r][m] = FLT_MAX; tk[r][m] = 0x7fffffff; }
    for (int kt = 0; kt < K; kt += BK) {
        float acc[4][8];
        #pragma unroll
        for (int r = 0; r < 4; ++r)
            #pragma unroll
            for (int cc = 0; cc < 8; ++cc) acc[r][cc] = 0.0f;
        for (int dt = 0; dt < D_DIM; dt += BD) {
            __syncthreads();
            #pragma unroll
            for (int i = 0; i < 2; ++i) {
                int lin = tid + i * 256;
                int zr = lin >> 3, dg = lin & 7;
                float4 v = *(const float4*)(z + (size_t)(row0 + zr) * D_DIM + dt + dg * 4);
                zs[dg * 4 + 0][zr] = v.x; zs[dg * 4 + 1][zr] = v.y;
                zs[dg * 4 + 2][zr] = v.z; zs[dg * 4 + 3][zr] = v.w;
            }
            #pragma unroll
            for (int i = 0; i < 4; ++i) {
                int lin = tid + i * 256;
                int cr = lin >> 3, dg = lin & 7;
                float4 v = *(const float4*)(cb + (size_t)(kt + cr) * D_DIM + dt + dg * 4);
                cs[dg * 4 + 0][cr] = v.x; cs[dg * 4 + 1][cr] = v.y;
                cs[dg * 4 + 2][cr] = v.z; cs[dg * 4 + 3][cr] = v.w;
            }
            __syncthreads();
            #pragma unroll
            for (int d = 0; d < BD; ++d) {
                float4 a = *(const float4*)&zs[d][rg * 4];
                float4 b0 = *(const float4*)&cs[d][cg * 8];
                float4 b1 = *(const float4*)&cs[d][cg * 8 + 4];
                float av[4] = {a.x, a.y, a.z, a.w};
                float bv[8] = {b0.x, b0.y, b0.z, b0.w, b1.x, b1.y, b1.z, b1.w};
                #pragma unroll
                for (int r = 0; r < 4; ++r)
                    #pragma unroll
                    for (int cc = 0; cc < 8; ++cc)
                        acc[r][cc] = fmaf(av[r], bv[cc], acc[r][cc]);
            }
        }
        #pragma unroll
        for (int cc = 0; cc < 8; ++cc) {
            int k = kt + cg * 8 + cc;
            float cq = csq32[k];
            #pragma unroll
            for (int r = 0; r < 4; ++r) {
                float s = fmaf(-2.0f, acc[r][cc], cq);
                top4_insert(tv[r], tk[r], s, k);
            }
        }
    }
    __syncthreads();
    #pragma unroll
    for (int r = 0; r < 4; ++r)
        #pragma unroll
        for (int m = 0; m < 4; ++m) {
            mvv[rg * 4 + r][cg * 4 + m] = tv[r][m];
            mii[rg * 4 + r][cg * 4 + m] = tk[r][m];
        }
    __syncthreads();
    if (tid < BM) {
        int row = tid;
        float bv[4] = {FLT_MAX, FLT_MAX, FLT_MAX, FLT_MAX};
        int   bk[4] = {0x7fffffff, 0x7fffffff, 0x7fffffff, 0x7fffffff};
        for (int j = 0; j < 64; ++j) top4_insert(bv, bk, mvv[row][j], mii[row][j]);
        #pragma unroll
        for (int m = 0; m < 4; ++m) {
            cand_v[(size_t)(row0 + row) * 4 + m] = bv[m];
            cand_i[(size_t)(row0 + row) * 4 + m] = bk[m];
        }
    }
}

__global__ __launch_bounds__(256) void pass2_kernel(const float* __restrict__ z,
                                                    const float* __restrict__ cb,
                                                    const double* __restrict__ csq64,
                                                    const float* __restrict__ cand_v,
                                                    const int* __restrict__ cand_i,
                                                    float* __restrict__ zq,
                                                    float* __restrict__ oidx,
                                                    float* __restrict__ freq,
                                                    int N, int K) {
    int lane = threadIdx.x & 63;
    int row = blockIdx.x * 4 + (threadIdx.x >> 6);
    if (row >= N) return;
    const float* zrow = z + (size_t)row * D_DIM;
    float4 z0 = *(const float4*)(zrow + lane * 4);
    float4 z1 = *(const float4*)(zrow + 256 + lane * 4);
    float cv0 = cand_v[(size_t)row * 4 + 0];
    float cv3 = cand_v[(size_t)row * 4 + 3];
    int ci[4];
    bool ok = (cv3 - cv0 >= 0.1f);
    #pragma unroll
    for (int m = 0; m < 4; ++m) {
        ci[m] = cand_i[(size_t)row * 4 + m];
        if (ci[m] < 0 || ci[m] >= K) ok = false;
    }
    double best_s = DBL_MAX;
    int best_k = 0;
    if (ok) {
        #pragma unroll
        for (int m = 0; m < 4; ++m) {
            int k = ci[m];
            const float* crow = cb + (size_t)k * D_DIM;
            float4 c0 = *(const float4*)(crow + lane * 4);
            float4 c1 = *(const float4*)(crow + 256 + lane * 4);
            double a = (double)z0.x * c0.x + (double)z0.y * c0.y +
                       (double)z0.z * c0.z + (double)z0.w * c0.w +
                       (double)z1.x * c1.x + (double)z1.y * c1.y +
                       (double)z1.z * c1.z + (double)z1.w * c1.w;
            #pragma unroll
            for (int off = 32; off > 0; off >>= 1) a += __shfl_down(a, off);
            if (lane == 0) {
                double s = csq64[k] - 2.0 * a;
                if (s < best_s || (s == best_s && k < best_k)) { best_s = s; best_k = k; }
            }
        }
    } else {
        for (int k = 0; k < K; ++k) {
            const float* crow = cb + (size_t)k * D_DIM;
            float4 c0 = *(const float4*)(crow + lane * 4);
            float4 c1 = *(const float4*)(crow + 256 + lane * 4);
            double a = (double)z0.x * c0.x + (double)z0.y * c0.y +
                       (double)z0.z * c0.z + (double)z0.w * c0.w +
                       (double)z1.x * c1.x + (double)z1.y * c1.y +
                       (double)z1.z * c1.z + (double)z1.w * c1.w;
            #pragma unroll
            for (int off = 32; off > 0; off >>= 1) a += __shfl_down(a, off);
            if (lane == 0) {
                double s = csq64[k] - 2.0 * a;
                if (s < best_s) { best_s = s; best_k = k; }
            }
        }
    }
    best_k = __shfl(best_k, 0);
    if (lane == 0) {
        oidx[row] = (float)best_k;
        atomicAdd(&freq[best_k], 1.0f);
    }
    const float* crow = cb + (size_t)best_k * D_DIM;
    *(float4*)(zq + (size_t)row * D_DIM + lane * 4) = *(const float4*)(crow + lane * 4);
    *(float4*)(zq + (size_t)row * D_DIM + 256 + lane * 4) = *(const float4*)(crow + 256 + lane * 4);
}

// ================= launcher ================================================
extern "C" void kernel_launch(void* const* d_in, const int* in_sizes, int n_in,
                              void* d_out, int out_size, void* d_ws, size_t ws_size,
                              hipStream_t stream) {
    const float* z  = (const float*)d_in[0];
    const float* cb = (const float*)d_in[1];
    const int N = in_sizes[0] / D_DIM;   // 32768
    const int K = in_sizes[1] / D_DIM;   // 4096

    float* zq   = (float*)d_out;
    float* oidx = zq + (size_t)N * D_DIM;
    float* freq = oidx + N;

    char* ws = (char*)d_ws;
    size_t o = 0;
    ushort_t* z_hi  = (ushort_t*)(ws + o); o += (size_t)N * D_DIM * 2;
    ushort_t* z_lo  = (ushort_t*)(ws + o); o += (size_t)N * D_DIM * 2;
    ushort_t* cbh   = (ushort_t*)(ws + o); o += (size_t)K * D_DIM * 2;
    ushort_t* cbl   = (ushort_t*)(ws + o); o += (size_t)K * D_DIM * 2;
    o = (o + 255) & ~(size_t)255;
    float*  csq32   = (float*)(ws + o);    o += (size_t)K * sizeof(float);
    o = (o + 255) & ~(size_t)255;
    double* csq64   = (double*)(ws + o);   o += (size_t)K * sizeof(double);
    o = (o + 255) & ~(size_t)255;
    int* cand_cnt   = (int*)(ws + o);      o += (size_t)N * sizeof(int);
    int* cand_kk    = (int*)(ws + o);      o += (size_t)N * 8 * sizeof(int);
    size_t needed = o;

    if (ws_size >= needed && (N % 128) == 0 && (K % 128) == 0) {
        long total8 = (long)N * D_DIM / 8;
        hipLaunchKernelGGL(split_z_kernel, dim3((unsigned)((total8 + 255) / 256)), dim3(256),
                           0, stream, z, z_hi, z_lo, total8);
        hipLaunchKernelGGL(split_cb_kernel, dim3(K / 4), dim3(256), 0, stream,
                           cb, cbh, cbl, csq32, csq64, freq, K);
        hipLaunchKernelGGL(pass1_mfma_kernel, dim3(N / 128), dim3(256), 65536, stream,
                           z_hi, z_lo, cbh, cbl, csq32, cand_cnt, cand_kk, K);
        hipLaunchKernelGGL(pass2_new_kernel, dim3(N / 4), dim3(256), 0, stream,
                           z, cb, csq64, cand_cnt, cand_kk, zq, oidx, freq, N, K);
    } else {
        // R2-passing f32 fallback (small ws footprint)
        size_t o2 = 0;
        float*  f_csq32 = (float*)(ws + o2);  o2 += (size_t)K * sizeof(float);
        o2 = (o2 + 255) & ~(size_t)255;
        double* f_csq64 = (double*)(ws + o2); o2 += (size_t)K * sizeof(double);
        o2 = (o2 + 255) & ~(size_t)255;
        float*  cand_v  = (float*)(ws + o2);  o2 += (size_t)N * 4 * sizeof(float);
        int*    cand_i  = (int*)(ws + o2);
        hipLaunchKernelGGL(csq_kernel, dim3((K + 3) / 4), dim3(256), 0, stream,
                           cb, f_csq32, f_csq64, freq, K);
        hipLaunchKernelGGL(pass1_kernel, dim3(N / BM), dim3(256), 0, stream,
                           z, cb, f_csq32, cand_v, cand_i, K);
        hipLaunchKernelGGL(pass2_kernel, dim3(N / 4), dim3(256), 0, stream,
                           z, cb, f_csq64, cand_v, cand_i, zq, oidx, freq, N, K);
    }
}

// Round 4
// 1727.537 us; speedup vs baseline: 1.8300x; 1.8300x over previous
//
#include <hip/hip_runtime.h>
#include <float.h>
#include <stdint.h>

#define D_DIM 512
#define MARGIN 0.05f  // = 2*e with e=0.025 >> true approx-score error bound (~5e-3)

typedef unsigned short ushort_t;
typedef unsigned int u32;
typedef __attribute__((ext_vector_type(8))) short short8v;     // 8 bf16 (4 VGPRs)
typedef __attribute__((ext_vector_type(8))) unsigned short ushort8v;
typedef __attribute__((ext_vector_type(4))) float f32x4;

__device__ __forceinline__ ushort_t f32_bf16_rne(float x) {
    u32 u = __float_as_uint(x);
    u32 r = (u + 0x7fffu + ((u >> 16) & 1u)) >> 16;
    return (ushort_t)r;
}
__device__ __forceinline__ float bf16_f32(ushort_t h) {
    return __uint_as_float(((u32)h) << 16);
}
__device__ __forceinline__ void gload_lds16(const void* g, void* l) {
    __builtin_amdgcn_global_load_lds(
        (const __attribute__((address_space(1))) u32*)(g),
        (__attribute__((address_space(3))) u32*)(l), 16, 0, 0);
}

// ============ prep: split z into bf16 hi/lo ================================
__global__ __launch_bounds__(256) void split_z_kernel(const float* __restrict__ z,
                                                      ushort_t* __restrict__ z_hi,
                                                      ushort_t* __restrict__ z_lo,
                                                      long total8) {
    long i = (long)blockIdx.x * 256 + threadIdx.x;
    if (i >= total8) return;
    const float4* p = (const float4*)(z + i * 8);
    float4 a = p[0], b = p[1];
    float x[8] = {a.x, a.y, a.z, a.w, b.x, b.y, b.z, b.w};
    ushort8v h, lo;
    #pragma unroll
    for (int j = 0; j < 8; ++j) {
        ushort_t hh = f32_bf16_rne(x[j]);
        h[j] = hh;
        lo[j] = f32_bf16_rne(x[j] - bf16_f32(hh));
    }
    *(ushort8v*)(z_hi + i * 8) = h;
    *(ushort8v*)(z_lo + i * 8) = lo;
}

// ============ prep: split codebook + norms (f32/f64) + zero freq ===========
__global__ __launch_bounds__(256) void split_cb_kernel(const float* __restrict__ cb,
                                                       ushort_t* __restrict__ cb_hi,
                                                       ushort_t* __restrict__ cb_lo,
                                                       float* __restrict__ csq32,
                                                       double* __restrict__ csq64,
                                                       float* __restrict__ freq,
                                                       int K) {
    int tid = threadIdx.x;
    int gt = blockIdx.x * 256 + tid;
    if (gt < K) freq[gt] = 0.0f;

    int wv = tid >> 6, lane = tid & 63;
    int k = blockIdx.x * 4 + wv;
    if (k >= K) return;
    const float* row = cb + (size_t)k * D_DIM;
    float4 a = *(const float4*)(row + lane * 8);
    float4 b = *(const float4*)(row + lane * 8 + 4);
    float x[8] = {a.x, a.y, a.z, a.w, b.x, b.y, b.z, b.w};
    ushort8v h, lo;
    double s = 0.0;
    #pragma unroll
    for (int j = 0; j < 8; ++j) {
        s += (double)x[j] * x[j];
        ushort_t hh = f32_bf16_rne(x[j]);
        h[j] = hh;
        lo[j] = f32_bf16_rne(x[j] - bf16_f32(hh));
    }
    *(ushort8v*)(cb_hi + (size_t)k * D_DIM + lane * 8) = h;
    *(ushort8v*)(cb_lo + (size_t)k * D_DIM + lane * 8) = lo;
    #pragma unroll
    for (int off = 32; off > 0; off >>= 1) s += __shfl_down(s, off);
    if (lane == 0) { csq64[k] = s; csq32[k] = (float)s; }
}

// ============ pass 1: split-bf16 MFMA GEMM + per-row candidates ============
// (unchanged from R3 — validated)
__global__ __launch_bounds__(256, 2) void pass1_mfma_kernel(
        const ushort_t* __restrict__ z_hi, const ushort_t* __restrict__ z_lo,
        const ushort_t* __restrict__ cb_hi, const ushort_t* __restrict__ cb_lo,
        const float* __restrict__ csq32,
        int* __restrict__ cand_cnt, int* __restrict__ cand_k, int K) {
    extern __shared__ char smem[];
    const int tid = threadIdx.x;
    const int wid = tid >> 6;
    const int lane = tid & 63;
    const int wm = wid >> 1, wn = wid & 1;
    const int c = lane & 15, g = lane >> 4;
    const int row0 = blockIdx.x * 128;

    f32x4 acc[4][4];
    float tv0[16], tv1[16]; int tk0[16], tk1[16];
    #pragma unroll
    for (int i = 0; i < 16; ++i) { tv0[i] = FLT_MAX; tv1[i] = FLT_MAX; tk0[i] = 0; tk1[i] = 0; }

    auto STAGE = [&](int buf, int ct_, int t_) {
        int seg = t_ >> 3;                 // 0: hi*hi, 1: hi*lo, 2: lo*hi
        int dtt = (t_ & 7) << 6;           // d-offset within segment
        const ushort_t* As = (seg == 2) ? z_lo : z_hi;
        const ushort_t* Bs = (seg == 1) ? cb_lo : cb_hi;
        int code0_ = ct_ << 7;
        #pragma unroll
        for (int r = 0; r < 4; ++r) {
            int s = r * 256 + tid;         // 16B slot id 0..1023
            int rw = s >> 3, p = s & 7;    // row 0..127, slot-in-row 0..7
            int dswz = dtt + ((p ^ (rw & 7)) << 3);   // pre-swizzled source
            gload_lds16(As + (size_t)(row0 + rw) * D_DIM + dswz,
                        smem + buf * 16384 + r * 4096 + wid * 1024);
            gload_lds16(Bs + (size_t)(code0_ + rw) * D_DIM + dswz,
                        smem + 32768 + buf * 16384 + r * 4096 + wid * 1024);
        }
    };

    auto COMPUTE = [&](int buf) {
        const char* Ab = smem + buf * 16384;
        const char* Bb = smem + 32768 + buf * 16384;
        #pragma unroll
        for (int ks = 0; ks < 2; ++ks) {
            int q = ks * 4 + g;            // logical 16B k-slot
            short8v a[4], b[4];
            #pragma unroll
            for (int fm = 0; fm < 4; ++fm) {
                int rl = wm * 64 + fm * 16 + c;
                a[fm] = *(const short8v*)(Ab + rl * 128 + ((q ^ (rl & 7)) << 4));
            }
            #pragma unroll
            for (int fn = 0; fn < 4; ++fn) {
                int cl = wn * 64 + fn * 16 + c;
                b[fn] = *(const short8v*)(Bb + cl * 128 + ((q ^ (cl & 7)) << 4));
            }
            #pragma unroll
            for (int fm = 0; fm < 4; ++fm)
                #pragma unroll
                for (int fn = 0; fn < 4; ++fn)
                    acc[fm][fn] = __builtin_amdgcn_mfma_f32_16x16x32_bf16(
                        a[fm], b[fn], acc[fm][fn], 0, 0, 0);
        }
    };

    STAGE(0, 0, 0);
    for (int ct = 0; ct < 32; ++ct) {
        f32x4 zz = {0.f, 0.f, 0.f, 0.f};
        #pragma unroll
        for (int fm = 0; fm < 4; ++fm)
            #pragma unroll
            for (int fn = 0; fn < 4; ++fn) acc[fm][fn] = zz;

        for (int t = 0; t < 24; ++t) {
            __syncthreads();               // stage(t) complete (vmcnt0 + barrier)
            if (t < 23)       STAGE((t + 1) & 1, ct, t + 1);
            else if (ct < 31) STAGE(0, ct + 1, 0);   // 24 even -> next ct starts buf0
            COMPUTE(t & 1);
        }

        // epilogue: scores + per-(thread,row) top-2 (registers only, no LDS)
        int code0 = ct << 7;
        float cq[4];
        #pragma unroll
        for (int fn = 0; fn < 4; ++fn) cq[fn] = csq32[code0 + wn * 64 + fn * 16 + c];
        #pragma unroll
        for (int fm = 0; fm < 4; ++fm)
            #pragma unroll
            for (int fn = 0; fn < 4; ++fn) {
                int code = code0 + wn * 64 + fn * 16 + c;
                #pragma unroll
                for (int rg = 0; rg < 4; ++rg) {
                    float sv = fmaf(-2.0f, acc[fm][fn][rg], cq[fn]);
                    int rp = fm * 4 + rg;
                    if (sv < tv1[rp]) {
                        if (sv < tv0[rp]) {
                            tv1[rp] = tv0[rp]; tk1[rp] = tk0[rp];
                            tv0[rp] = sv;      tk0[rp] = code;
                        } else { tv1[rp] = sv; tk1[rp] = code; }
                    }
                }
            }
    }

    // ---- merge 64 candidates/row (32 threads x top-2), prove coverage ----
    __syncthreads();                       // all compute done; staging LDS reusable
    float* mv = (float*)smem;              // [128][64]
    int*   mi = (int*)(smem + 32768);      // [128][64]
    #pragma unroll
    for (int fm = 0; fm < 4; ++fm)
        #pragma unroll
        for (int rg = 0; rg < 4; ++rg) {
            int rl = wm * 64 + fm * 16 + g * 4 + rg;   // C row mapping
            int slot = wn * 16 + c;
            int rp = fm * 4 + rg;
            mv[rl * 64 + slot * 2]     = tv0[rp];
            mv[rl * 64 + slot * 2 + 1] = tv1[rp];
            mi[rl * 64 + slot * 2]     = tk0[rp];
            mi[rl * 64 + slot * 2 + 1] = tk1[rp];
        }
    __syncthreads();
    if (tid < 128) {
        const float* rv = mv + tid * 64;
        const int*   ri = mi + tid * 64;
        float v0 = FLT_MAX, w = FLT_MAX;
        for (int j = 0; j < 64; ++j) v0 = fminf(v0, rv[j]);
        for (int j = 1; j < 64; j += 2) w = fminf(w, rv[j]);  // min of lane-seconds
        float lim = v0 + MARGIN;
        int cnt = 0; int ks[8];
        for (int j = 0; j < 64; ++j)
            if (rv[j] <= lim) { if (cnt < 8) ks[cnt] = ri[j]; cnt++; }
        // coverage proof: every non-candidate code scores >= its slot's 2nd >= w
        bool ok = (w - v0 >= MARGIN) && (cnt >= 1) && (cnt <= 8);
        int gr = row0 + tid;
        if (!ok) cand_cnt[gr] = 0;         // rare: wave-parallel f64 scan in pass 2
        else {
            cand_cnt[gr] = cnt;
            for (int m = 0; m < cnt; ++m) cand_k[gr * 8 + m] = ks[m];
        }
    }
}

// ============ pass 2: f64 rescore of filtered candidates + outputs =========
__global__ __launch_bounds__(256) void pass2_new_kernel(
        const float* __restrict__ z, const float* __restrict__ cb,
        const double* __restrict__ csq64,
        const int* __restrict__ cand_cnt, const int* __restrict__ cand_k,
        float* __restrict__ zq, float* __restrict__ oidx, float* __restrict__ freq,
        int N, int K) {
    int lane = threadIdx.x & 63;
    int row = blockIdx.x * 4 + (threadIdx.x >> 6);
    if (row >= N) return;

    int cnt = cand_cnt[row];
    int best_k;
    if (cnt == 1) {
        best_k = cand_k[(size_t)row * 8];
    } else if (cnt >= 2) {
        // d-parallel f64 rescore of <=8 candidates
        const float* zrow = z + (size_t)row * D_DIM;
        float4 z0 = *(const float4*)(zrow + lane * 4);
        float4 z1 = *(const float4*)(zrow + 256 + lane * 4);
        double best_s = DBL_MAX; int bk = 0x7fffffff;
        for (int m = 0; m < cnt; ++m) {
            int k = cand_k[(size_t)row * 8 + m];
            const float* crow = cb + (size_t)k * D_DIM;
            float4 c0 = *(const float4*)(crow + lane * 4);
            float4 c1 = *(const float4*)(crow + 256 + lane * 4);
            double a = (double)z0.x * c0.x + (double)z0.y * c0.y +
                       (double)z0.z * c0.z + (double)z0.w * c0.w +
                       (double)z1.x * c1.x + (double)z1.y * c1.y +
                       (double)z1.z * c1.z + (double)z1.w * c1.w;
            #pragma unroll
            for (int off = 32; off > 0; off >>= 1) a += __shfl_down(a, off);
            if (lane == 0) {
                double s = csq64[k] - 2.0 * a;
                if (s < best_s || (s == best_s && k < bk)) { best_s = s; bk = k; }
            }
        }
        best_k = __shfl(bk, 0);
    } else {
        // rare coverage failure: wave-parallel exact f64 scan, code-parallel.
        // Lane owns code kb+lane; z row read via wave-uniform broadcast (L1-hot),
        // codebook rows per-lane from L2/L3. No cross-lane dependency until the
        // final min-reduce -> ~60us instead of the serial 1.9ms that caused R3's tail.
        const float* zrow = z + (size_t)row * D_DIM;
        double bs = DBL_MAX; int bk = 0x7fffffff;
        for (int kb = 0; kb < K; kb += 64) {
            int k = kb + lane;
            const float* crow = cb + (size_t)k * D_DIM;
            double a = 0.0;
            #pragma unroll 4
            for (int d = 0; d < D_DIM; d += 4) {
                float4 zv = *(const float4*)(zrow + d);   // uniform across lanes
                float4 cv = *(const float4*)(crow + d);   // per-lane row
                a += (double)zv.x * cv.x + (double)zv.y * cv.y +
                     (double)zv.z * cv.z + (double)zv.w * cv.w;
            }
            double s = csq64[k] - 2.0 * a;
            if (s < bs) { bs = s; bk = k; }   // per-lane k strictly increasing
        }
        #pragma unroll
        for (int off = 32; off > 0; off >>= 1) {
            double os = __shfl_down(bs, off);
            int    ok2 = __shfl_down(bk, off);
            if (os < bs || (os == bs && ok2 < bk)) { bs = os; bk = ok2; }
        }
        best_k = __shfl(bk, 0);
    }

    if (lane == 0) {
        oidx[row] = (float)best_k;
        atomicAdd(&freq[best_k], 1.0f);
    }
    // gather z_q = codebook[best_k] (exact -> bitwise match)
    const float* crow = cb + (size_t)best_k * D_DIM;
    *(float4*)(zq + (size_t)row * D_DIM + lane * 4) = *(const float4*)(crow + lane * 4);
    *(float4*)(zq + (size_t)row * D_DIM + 256 + lane * 4) = *(const float4*)(crow + 256 + lane * 4);
}

// ================= fallback path (R2-passing f32 pipeline) =================
__global__ __launch_bounds__(256) void csq_kernel(const float* __restrict__ cb,
                                                  float* __restrict__ csq32,
                                                  double* __restrict__ csq64,
                                                  float* __restrict__ freq,
                                                  int K) {
    int tid = threadIdx.x;
    int gt = blockIdx.x * 256 + tid;
    if (gt < K) freq[gt] = 0.0f;
    int wave = tid >> 6, lane = tid & 63;
    int k = blockIdx.x * 4 + wave;
    if (k >= K) return;
    const float* row = cb + (size_t)k * D_DIM;
    float4 v0 = *(const float4*)(row + lane * 4);
    float4 v1 = *(const float4*)(row + 256 + lane * 4);
    double s = (double)v0.x * v0.x + (double)v0.y * v0.y +
               (double)v0.z * v0.z + (double)v0.w * v0.w +
               (double)v1.x * v1.x + (double)v1.y * v1.y +
               (double)v1.z * v1.z + (double)v1.w * v1.w;
    #pragma unroll
    for (int off = 32; off > 0; off >>= 1) s += __shfl_down(s, off);
    if (lane == 0) { csq64[k] = s; csq32[k] = (float)s; }
}

__device__ __forceinline__ void top4_insert(float (&v)[4], int (&ki)[4], float s, int k) {
    if (s < v[3]) {
        v[3] = s; ki[3] = k;
        if (v[3] < v[2]) {
            float t = v[3]; v[3] = v[2]; v[2] = t; int u = ki[3]; ki[3] = ki[2]; ki[2] = u;
            if (v[2] < v[1]) {
                t = v[2]; v[2] = v[1]; v[1] = t; u = ki[2]; ki[2] = ki[1]; ki[1] = u;
                if (v[1] < v[0]) {
                    t = v[1]; v[1] = v[0]; v[0] = t; u = ki[1]; ki[1] = ki[0]; ki[0] = u;
                }
            }
        }
    }
}

#define BM 64
#define BK 128
#define BD 32
#define ZS_STRIDE (BM + 4)
#define CS_STRIDE (BK + 4)

__global__ __launch_bounds__(256) void pass1_kernel(const float* __restrict__ z,
                                                    const float* __restrict__ cb,
                                                    const float* __restrict__ csq32,
                                                    float* __restrict__ cand_v,
                                                    int* __restrict__ cand_i,
                                                    int K) {
    __shared__ float zs[BD][ZS_STRIDE];
    __shared__ float cs[BD][CS_STRIDE];
    __shared__ float mvv[BM][64];
    __shared__ int   mii[BM][64];
    const int tid = threadIdx.x;
    const int rg = tid & 15;
    const int cg = tid >> 4;
    const int row0 = blockIdx.x * BM;
    float tv[4][4]; int tk[4][4];
    #pragma unroll
    for (int r = 0; r < 4; ++r)
        #pragma unroll
        for (int m = 0; m < 4; ++m) { tv[r][m] = FLT_MAX; tk[r][m] = 0x7fffffff; }
    for (int kt = 0; kt < K; kt += BK) {
        float acc[4][8];
        #pragma unroll
        for (int r = 0; r < 4; ++r)
            #pragma unroll
            for (int cc = 0; cc < 8; ++cc) acc[r][cc] = 0.0f;
        for (int dt = 0; dt < D_DIM; dt += BD) {
            __syncthreads();
            #pragma unroll
            for (int i = 0; i < 2; ++i) {
                int lin = tid + i * 256;
                int zr = lin >> 3, dg = lin & 7;
                float4 v = *(const float4*)(z + (size_t)(row0 + zr) * D_DIM + dt + dg * 4);
                zs[dg * 4 + 0][zr] = v.x; zs[dg * 4 + 1][zr] = v.y;
                zs[dg * 4 + 2][zr] = v.z; zs[dg * 4 + 3][zr] = v.w;
            }
            #pragma unroll
            for (int i = 0; i < 4; ++i) {
                int lin = tid + i * 256;
                int cr = lin >> 3, dg = lin & 7;
                float4 v = *(const float4*)(cb + (size_t)(kt + cr) * D_DIM + dt + dg * 4);
                cs[dg * 4 + 0][cr] = v.x; cs[dg * 4 + 1][cr] = v.y;
                cs[dg * 4 + 2][cr] = v.z; cs[dg * 4 + 3][cr] = v.w;
            }
            __syncthreads();
            #pragma unroll
            for (int d = 0; d < BD; ++d) {
                float4 a = *(const float4*)&zs[d][rg * 4];
                float4 b0 = *(const float4*)&cs[d][cg * 8];
                float4 b1 = *(const float4*)&cs[d][cg * 8 + 4];
                float av[4] = {a.x, a.y, a.z, a.w};
                float bv[8] = {b0.x, b0.y, b0.z, b0.w, b1.x, b1.y, b1.z, b1.w};
                #pragma unroll
                for (int r = 0; r < 4; ++r)
                    #pragma unroll
                    for (int cc = 0; cc < 8; ++cc)
                        acc[r][cc] = fmaf(av[r], bv[cc], acc[r][cc]);
            }
        }
        #pragma unroll
        for (int cc = 0; cc < 8; ++cc) {
            int k = kt + cg * 8 + cc;
            float cq = csq32[k];
            #pragma unroll
            for (int r = 0; r < 4; ++r) {
                float s = fmaf(-2.0f, acc[r][cc], cq);
                top4_insert(tv[r], tk[r], s, k);
            }
        }
    }
    __syncthreads();
    #pragma unroll
    for (int r = 0; r < 4; ++r)
        #pragma unroll
        for (int m = 0; m < 4; ++m) {
            mvv[rg * 4 + r][cg * 4 + m] = tv[r][m];
            mii[rg * 4 + r][cg * 4 + m] = tk[r][m];
        }
    __syncthreads();
    if (tid < BM) {
        int row = tid;
        float bv[4] = {FLT_MAX, FLT_MAX, FLT_MAX, FLT_MAX};
        int   bk[4] = {0x7fffffff, 0x7fffffff, 0x7fffffff, 0x7fffffff};
        for (int j = 0; j < 64; ++j) top4_insert(bv, bk, mvv[row][j], mii[row][j]);
        #pragma unroll
        for (int m = 0; m < 4; ++m) {
            cand_v[(size_t)(row0 + row) * 4 + m] = bv[m];
            cand_i[(size_t)(row0 + row) * 4 + m] = bk[m];
        }
    }
}

__global__ __launch_bounds__(256) void pass2_kernel(const float* __restrict__ z,
                                                    const float* __restrict__ cb,
                                                    const double* __restrict__ csq64,
                                                    const float* __restrict__ cand_v,
                                                    const int* __restrict__ cand_i,
                                                    float* __restrict__ zq,
                                                    float* __restrict__ oidx,
                                                    float* __restrict__ freq,
                                                    int N, int K) {
    int lane = threadIdx.x & 63;
    int row = blockIdx.x * 4 + (threadIdx.x >> 6);
    if (row >= N) return;
    const float* zrow = z + (size_t)row * D_DIM;
    float4 z0 = *(const float4*)(zrow + lane * 4);
    float4 z1 = *(const float4*)(zrow + 256 + lane * 4);
    float cv0 = cand_v[(size_t)row * 4 + 0];
    float cv3 = cand_v[(size_t)row * 4 + 3];
    int ci[4];
    bool ok = (cv3 - cv0 >= 0.1f);
    #pragma unroll
    for (int m = 0; m < 4; ++m) {
        ci[m] = cand_i[(size_t)row * 4 + m];
        if (ci[m] < 0 || ci[m] >= K) ok = false;
    }
    double best_s = DBL_MAX;
    int best_k = 0;
    if (ok) {
        #pragma unroll
        for (int m = 0; m < 4; ++m) {
            int k = ci[m];
            const float* crow = cb + (size_t)k * D_DIM;
            float4 c0 = *(const float4*)(crow + lane * 4);
            float4 c1 = *(const float4*)(crow + 256 + lane * 4);
            double a = (double)z0.x * c0.x + (double)z0.y * c0.y +
                       (double)z0.z * c0.z + (double)z0.w * c0.w +
                       (double)z1.x * c1.x + (double)z1.y * c1.y +
                       (double)z1.z * c1.z + (double)z1.w * c1.w;
            #pragma unroll
            for (int off = 32; off > 0; off >>= 1) a += __shfl_down(a, off);
            if (lane == 0) {
                double s = csq64[k] - 2.0 * a;
                if (s < best_s || (s == best_s && k < best_k)) { best_s = s; best_k = k; }
            }
        }
    } else {
        for (int k = 0; k < K; ++k) {
            const float* crow = cb + (size_t)k * D_DIM;
            float4 c0 = *(const float4*)(crow + lane * 4);
            float4 c1 = *(const float4*)(crow + 256 + lane * 4);
            double a = (double)z0.x * c0.x + (double)z0.y * c0.y +
                       (double)z0.z * c0.z + (double)z0.w * c0.w +
                       (double)z1.x * c1.x + (double)z1.y * c1.y +
                       (double)z1.z * c1.z + (double)z1.w * c1.w;
            #pragma unroll
            for (int off = 32; off > 0; off >>= 1) a += __shfl_down(a, off);
            if (lane == 0) {
                double s = csq64[k] - 2.0 * a;
                if (s < best_s) { best_s = s; best_k = k; }
            }
        }
    }
    best_k = __shfl(best_k, 0);
    if (lane == 0) {
        oidx[row] = (float)best_k;
        atomicAdd(&freq[best_k], 1.0f);
    }
    const float* crow = cb + (size_t)best_k * D_DIM;
    *(float4*)(zq + (size_t)row * D_DIM + lane * 4) = *(const float4*)(crow + lane * 4);
    *(float4*)(zq + (size_t)row * D_DIM + 256 + lane * 4) = *(const float4*)(crow + 256 + lane * 4);
}

// ================= launcher ================================================
extern "C" void kernel_launch(void* const* d_in, const int* in_sizes, int n_in,
                              void* d_out, int out_size, void* d_ws, size_t ws_size,
                              hipStream_t stream) {
    const float* z  = (const float*)d_in[0];
    const float* cb = (const float*)d_in[1];
    const int N = in_sizes[0] / D_DIM;   // 32768
    const int K = in_sizes[1] / D_DIM;   // 4096

    float* zq   = (float*)d_out;
    float* oidx = zq + (size_t)N * D_DIM;
    float* freq = oidx + N;

    char* ws = (char*)d_ws;
    size_t o = 0;
    ushort_t* z_hi  = (ushort_t*)(ws + o); o += (size_t)N * D_DIM * 2;
    ushort_t* z_lo  = (ushort_t*)(ws + o); o += (size_t)N * D_DIM * 2;
    ushort_t* cbh   = (ushort_t*)(ws + o); o += (size_t)K * D_DIM * 2;
    ushort_t* cbl   = (ushort_t*)(ws + o); o += (size_t)K * D_DIM * 2;
    o = (o + 255) & ~(size_t)255;
    float*  csq32   = (float*)(ws + o);    o += (size_t)K * sizeof(float);
    o = (o + 255) & ~(size_t)255;
    double* csq64   = (double*)(ws + o);   o += (size_t)K * sizeof(double);
    o = (o + 255) & ~(size_t)255;
    int* cand_cnt   = (int*)(ws + o);      o += (size_t)N * sizeof(int);
    int* cand_kk    = (int*)(ws + o);      o += (size_t)N * 8 * sizeof(int);
    size_t needed = o;

    if (ws_size >= needed && (N % 128) == 0 && (K % 128) == 0) {
        long total8 = (long)N * D_DIM / 8;
        hipLaunchKernelGGL(split_z_kernel, dim3((unsigned)((total8 + 255) / 256)), dim3(256),
                           0, stream, z, z_hi, z_lo, total8);
        hipLaunchKernelGGL(split_cb_kernel, dim3(K / 4), dim3(256), 0, stream,
                           cb, cbh, cbl, csq32, csq64, freq, K);
        hipLaunchKernelGGL(pass1_mfma_kernel, dim3(N / 128), dim3(256), 65536, stream,
                           z_hi, z_lo, cbh, cbl, csq32, cand_cnt, cand_kk, K);
        hipLaunchKernelGGL(pass2_new_kernel, dim3(N / 4), dim3(256), 0, stream,
                           z, cb, csq64, cand_cnt, cand_kk, zq, oidx, freq, N, K);
    } else {
        // R2-passing f32 fallback (small ws footprint)
        size_t o2 = 0;
        float*  f_csq32 = (float*)(ws + o2);  o2 += (size_t)K * sizeof(float);
        o2 = (o2 + 255) & ~(size_t)255;
        double* f_csq64 = (double*)(ws + o2); o2 += (size_t)K * sizeof(double);
        o2 = (o2 + 255) & ~(size_t)255;
        float*  cand_v  = (float*)(ws + o2);  o2 += (size_t)N * 4 * sizeof(float);
        int*    cand_i  = (int*)(ws + o2);
        hipLaunchKernelGGL(csq_kernel, dim3((K + 3) / 4), dim3(256), 0, stream,
                           cb, f_csq32, f_csq64, freq, K);
        hipLaunchKernelGGL(pass1_kernel, dim3(N / BM), dim3(256), 0, stream,
                           z, cb, f_csq32, cand_v, cand_i, K);
        hipLaunchKernelGGL(pass2_kernel, dim3(N / 4), dim3(256), 0, stream,
                           z, cb, f_csq64, cand_v, cand_i, zq, oidx, freq, N, K);
    }
}

// Round 5
// 1586.799 us; speedup vs baseline: 1.9923x; 1.0887x over previous
//
#include <hip/hip_runtime.h>
#include <float.h>
#include <stdint.h>

#define D_DIM 512
#define MARGIN 0.05f  // = 2*e with e=0.025 >> true approx-score error bound (~5e-3)

typedef unsigned short ushort_t;
typedef unsigned int u32;
typedef __attribute__((ext_vector_type(8))) short short8v;     // 8 bf16 (4 VGPRs)
typedef __attribute__((ext_vector_type(8))) unsigned short ushort8v;
typedef __attribute__((ext_vector_type(4))) float f32x4;

__device__ __forceinline__ ushort_t f32_bf16_rne(float x) {
    u32 u = __float_as_uint(x);
    u32 r = (u + 0x7fffu + ((u >> 16) & 1u)) >> 16;
    return (ushort_t)r;
}
__device__ __forceinline__ float bf16_f32(ushort_t h) {
    return __uint_as_float(((u32)h) << 16);
}
__device__ __forceinline__ void gload_lds16(const void* g, void* l) {
    __builtin_amdgcn_global_load_lds(
        (const __attribute__((address_space(1))) u32*)(g),
        (__attribute__((address_space(3))) u32*)(l), 16, 0, 0);
}

// ============ prep: split z into bf16 hi/lo ================================
__global__ __launch_bounds__(256) void split_z_kernel(const float* __restrict__ z,
                                                      ushort_t* __restrict__ z_hi,
                                                      ushort_t* __restrict__ z_lo,
                                                      long total8) {
    long i = (long)blockIdx.x * 256 + threadIdx.x;
    if (i >= total8) return;
    const float4* p = (const float4*)(z + i * 8);
    float4 a = p[0], b = p[1];
    float x[8] = {a.x, a.y, a.z, a.w, b.x, b.y, b.z, b.w};
    ushort8v h, lo;
    #pragma unroll
    for (int j = 0; j < 8; ++j) {
        ushort_t hh = f32_bf16_rne(x[j]);
        h[j] = hh;
        lo[j] = f32_bf16_rne(x[j] - bf16_f32(hh));
    }
    *(ushort8v*)(z_hi + i * 8) = h;
    *(ushort8v*)(z_lo + i * 8) = lo;
}

// ============ prep: split codebook + norms (f32/f64) + zero freq ===========
__global__ __launch_bounds__(256) void split_cb_kernel(const float* __restrict__ cb,
                                                       ushort_t* __restrict__ cb_hi,
                                                       ushort_t* __restrict__ cb_lo,
                                                       float* __restrict__ csq32,
                                                       double* __restrict__ csq64,
                                                       float* __restrict__ freq,
                                                       int K) {
    int tid = threadIdx.x;
    int gt = blockIdx.x * 256 + tid;
    if (gt < K) freq[gt] = 0.0f;

    int wv = tid >> 6, lane = tid & 63;
    int k = blockIdx.x * 4 + wv;
    if (k >= K) return;
    const float* row = cb + (size_t)k * D_DIM;
    float4 a = *(const float4*)(row + lane * 8);
    float4 b = *(const float4*)(row + lane * 8 + 4);
    float x[8] = {a.x, a.y, a.z, a.w, b.x, b.y, b.z, b.w};
    ushort8v h, lo;
    double s = 0.0;
    #pragma unroll
    for (int j = 0; j < 8; ++j) {
        s += (double)x[j] * x[j];
        ushort_t hh = f32_bf16_rne(x[j]);
        h[j] = hh;
        lo[j] = f32_bf16_rne(x[j] - bf16_f32(hh));
    }
    *(ushort8v*)(cb_hi + (size_t)k * D_DIM + lane * 8) = h;
    *(ushort8v*)(cb_lo + (size_t)k * D_DIM + lane * 8) = lo;
    #pragma unroll
    for (int off = 32; off > 0; off >>= 1) s += __shfl_down(s, off);
    if (lane == 0) { csq64[k] = s; csq32[k] = (float)s; }
}

// ============ pass 1: split-bf16 MFMA GEMM + per-(row,half) candidates =====
// Grid (N/128, 2): blockIdx.y = code half (16 code tiles each) -> 512 blocks,
// 2 blocks/CU (LDS 2x64KB=128KB <= 160KB) so barrier/vmcnt drains overlap.
__global__ __launch_bounds__(256, 2) void pass1_mfma_kernel(
        const ushort_t* __restrict__ z_hi, const ushort_t* __restrict__ z_lo,
        const ushort_t* __restrict__ cb_hi, const ushort_t* __restrict__ cb_lo,
        const float* __restrict__ csq32,
        float* __restrict__ cm_v0, float* __restrict__ cm_w,
        int* __restrict__ cm_cnt,
        float* __restrict__ cand_v, int* __restrict__ cand_k, int K) {
    extern __shared__ char smem[];
    const int tid = threadIdx.x;
    const int wid = tid >> 6;
    const int lane = tid & 63;
    const int wm = wid >> 1, wn = wid & 1;
    const int c = lane & 15, g = lane >> 4;
    const int row0 = blockIdx.x * 128;
    const int half = blockIdx.y;
    const int ct0 = half * 16;

    f32x4 acc[4][4];
    float tv0[16], tv1[16]; int tk0[16], tk1[16];
    #pragma unroll
    for (int i = 0; i < 16; ++i) { tv0[i] = FLT_MAX; tv1[i] = FLT_MAX; tk0[i] = 0; tk1[i] = 0; }

    auto STAGE = [&](int buf, int ct_, int t_) {
        int seg = t_ >> 3;                 // 0: hi*hi, 1: hi*lo, 2: lo*hi
        int dtt = (t_ & 7) << 6;           // d-offset within segment
        const ushort_t* As = (seg == 2) ? z_lo : z_hi;
        const ushort_t* Bs = (seg == 1) ? cb_lo : cb_hi;
        int code0_ = ct_ << 7;
        #pragma unroll
        for (int r = 0; r < 4; ++r) {
            int s = r * 256 + tid;         // 16B slot id 0..1023
            int rw = s >> 3, p = s & 7;    // row 0..127, slot-in-row 0..7
            int dswz = dtt + ((p ^ (rw & 7)) << 3);   // pre-swizzled source
            gload_lds16(As + (size_t)(row0 + rw) * D_DIM + dswz,
                        smem + buf * 16384 + r * 4096 + wid * 1024);
            gload_lds16(Bs + (size_t)(code0_ + rw) * D_DIM + dswz,
                        smem + 32768 + buf * 16384 + r * 4096 + wid * 1024);
        }
    };

    auto COMPUTE = [&](int buf) {
        const char* Ab = smem + buf * 16384;
        const char* Bb = smem + 32768 + buf * 16384;
        #pragma unroll
        for (int ks = 0; ks < 2; ++ks) {
            int q = ks * 4 + g;            // logical 16B k-slot
            short8v a[4], b[4];
            #pragma unroll
            for (int fm = 0; fm < 4; ++fm) {
                int rl = wm * 64 + fm * 16 + c;
                a[fm] = *(const short8v*)(Ab + rl * 128 + ((q ^ (rl & 7)) << 4));
            }
            #pragma unroll
            for (int fn = 0; fn < 4; ++fn) {
                int cl = wn * 64 + fn * 16 + c;
                b[fn] = *(const short8v*)(Bb + cl * 128 + ((q ^ (cl & 7)) << 4));
            }
            #pragma unroll
            for (int fm = 0; fm < 4; ++fm)
                #pragma unroll
                for (int fn = 0; fn < 4; ++fn)
                    acc[fm][fn] = __builtin_amdgcn_mfma_f32_16x16x32_bf16(
                        a[fm], b[fn], acc[fm][fn], 0, 0, 0);
        }
    };

    STAGE(0, ct0, 0);
    for (int ci = 0; ci < 16; ++ci) {
        int ct = ct0 + ci;
        f32x4 zz = {0.f, 0.f, 0.f, 0.f};
        #pragma unroll
        for (int fm = 0; fm < 4; ++fm)
            #pragma unroll
            for (int fn = 0; fn < 4; ++fn) acc[fm][fn] = zz;

        for (int t = 0; t < 24; ++t) {
            __syncthreads();               // stage(t) complete (vmcnt0 + barrier)
            if (t < 23)       STAGE((t + 1) & 1, ct, t + 1);
            else if (ci < 15) STAGE(0, ct + 1, 0);   // 24 even -> next ct starts buf0
            COMPUTE(t & 1);
        }

        // epilogue: scores + per-(thread,row) top-2 (registers only)
        int code0 = ct << 7;
        float cq[4];
        #pragma unroll
        for (int fn = 0; fn < 4; ++fn) cq[fn] = csq32[code0 + wn * 64 + fn * 16 + c];
        #pragma unroll
        for (int fm = 0; fm < 4; ++fm)
            #pragma unroll
            for (int fn = 0; fn < 4; ++fn) {
                int code = code0 + wn * 64 + fn * 16 + c;
                #pragma unroll
                for (int rg = 0; rg < 4; ++rg) {
                    float sv = fmaf(-2.0f, acc[fm][fn][rg], cq[fn]);
                    int rp = fm * 4 + rg;
                    if (sv < tv1[rp]) {
                        if (sv < tv0[rp]) {
                            tv1[rp] = tv0[rp]; tk1[rp] = tk0[rp];
                            tv0[rp] = sv;      tk0[rp] = code;
                        } else { tv1[rp] = sv; tk1[rp] = code; }
                    }
                }
            }
    }

    // ---- merge 64 candidates/row (32 slots x top-2) for this half ----
    __syncthreads();                       // staging LDS reusable
    float* mv = (float*)smem;              // [128][64]
    int*   mi = (int*)(smem + 32768);      // [128][64]
    #pragma unroll
    for (int fm = 0; fm < 4; ++fm)
        #pragma unroll
        for (int rg = 0; rg < 4; ++rg) {
            int rl = wm * 64 + fm * 16 + g * 4 + rg;   // C row mapping
            int slot = wn * 16 + c;
            int rp = fm * 4 + rg;
            mv[rl * 64 + slot * 2]     = tv0[rp];
            mv[rl * 64 + slot * 2 + 1] = tv1[rp];
            mi[rl * 64 + slot * 2]     = tk0[rp];
            mi[rl * 64 + slot * 2 + 1] = tk1[rp];
        }
    __syncthreads();
    if (tid < 128) {
        const float* rv = mv + tid * 64;
        const int*   ri = mi + tid * 64;
        float v0 = FLT_MAX, w = FLT_MAX;
        for (int j = 0; j < 64; ++j) v0 = fminf(v0, rv[j]);
        for (int j = 1; j < 64; j += 2) w = fminf(w, rv[j]);  // min of slot-seconds
        float lim = v0 + MARGIN;
        int cnt = 0; int ks[8]; float vs[8];
        for (int j = 0; j < 64; ++j)
            if (rv[j] <= lim) {
                if (cnt < 8) { ks[cnt] = ri[j]; vs[cnt] = rv[j]; }
                cnt++;
            }
        int gidx = (row0 + tid) * 2 + half;
        cm_v0[gidx] = v0;
        cm_w[gidx]  = w;
        cm_cnt[gidx] = cnt;                // >8 means overflow -> pass2 full scan
        int st = cnt < 8 ? cnt : 8;
        for (int m = 0; m < st; ++m) {
            cand_v[(size_t)gidx * 8 + m] = vs[m];
            cand_k[(size_t)gidx * 8 + m] = ks[m];
        }
    }
}

// ============ pass 2: merge halves, f64 rescore, outputs ===================
__global__ __launch_bounds__(256) void pass2_new_kernel(
        const float* __restrict__ z, const float* __restrict__ cb,
        const double* __restrict__ csq64,
        const float* __restrict__ cm_v0, const float* __restrict__ cm_w,
        const int* __restrict__ cm_cnt,
        const float* __restrict__ cand_v, const int* __restrict__ cand_k,
        float* __restrict__ zq, float* __restrict__ oidx, float* __restrict__ freq,
        int N, int K) {
    int lane = threadIdx.x & 63;
    int row = blockIdx.x * 4 + (threadIdx.x >> 6);
    if (row >= N) return;

    float v0a = cm_v0[row * 2], v0b = cm_v0[row * 2 + 1];
    float wa  = cm_w[row * 2],  wb  = cm_w[row * 2 + 1];
    int   na  = cm_cnt[row * 2], nb = cm_cnt[row * 2 + 1];
    float v0g = fminf(v0a, v0b);
    float wmn = fminf(wa, wb);
    bool bad = (na > 8) || (nb > 8) || (wmn - v0g < MARGIN) || (na < 0) || (nb < 0);

    int best_k;
    if (!bad) {
        // union of half-candidates filtered by global limit (provably covers)
        float lim = v0g + MARGIN;
        int ks[16]; int cnt = 0;
        #pragma unroll
        for (int h = 0; h < 2; ++h) {
            int cc = h ? nb : na;
            for (int m = 0; m < cc; ++m) {
                size_t idx = (size_t)(row * 2 + h) * 8 + m;
                if (cand_v[idx] <= lim) ks[cnt++] = cand_k[idx];
            }
        }
        if (cnt == 1) {
            best_k = ks[0];
        } else {
            const float* zrow = z + (size_t)row * D_DIM;
            float4 z0 = *(const float4*)(zrow + lane * 4);
            float4 z1 = *(const float4*)(zrow + 256 + lane * 4);
            double best_s = DBL_MAX; int bk = 0x7fffffff;
            for (int m = 0; m < cnt; ++m) {
                int k = ks[m];
                const float* crow = cb + (size_t)k * D_DIM;
                float4 c0 = *(const float4*)(crow + lane * 4);
                float4 c1 = *(const float4*)(crow + 256 + lane * 4);
                double a = (double)z0.x * c0.x + (double)z0.y * c0.y +
                           (double)z0.z * c0.z + (double)z0.w * c0.w +
                           (double)z1.x * c1.x + (double)z1.y * c1.y +
                           (double)z1.z * c1.z + (double)z1.w * c1.w;
                #pragma unroll
                for (int off = 32; off > 0; off >>= 1) a += __shfl_down(a, off);
                if (lane == 0) {
                    double s = csq64[k] - 2.0 * a;
                    if (s < best_s || (s == best_s && k < bk)) { best_s = s; bk = k; }
                }
            }
            best_k = __shfl(bk, 0);
        }
    } else {
        // rare coverage failure: exact f64 scan, 8 codes/iter x 8 lanes/code.
        // Wave reads 16KB contiguous per iter (perfectly coalesced); z chunk
        // hoisted to registers; 4 independent f64 accumulators.
        const int cs = lane >> 3;          // code sub-index 0..7
        const int ds = lane & 7;           // d-chunk 0..7 (64 floats each)
        const float* zch = z + (size_t)row * D_DIM + ds * 64;
        float4 zr[16];
        #pragma unroll
        for (int j = 0; j < 16; ++j) zr[j] = *(const float4*)(zch + j * 4);

        double bs = DBL_MAX; int bk = 0x7fffffff;
        for (int kb = 0; kb < K; kb += 8) {
            int k = kb + cs;
            const float* crow = cb + (size_t)k * D_DIM + ds * 64;
            double a0 = 0.0, a1 = 0.0, a2 = 0.0, a3 = 0.0;
            #pragma unroll
            for (int j = 0; j < 16; j += 4) {
                float4 c0 = *(const float4*)(crow + j * 4);
                float4 c1 = *(const float4*)(crow + j * 4 + 4);
                float4 c2 = *(const float4*)(crow + j * 4 + 8);
                float4 c3 = *(const float4*)(crow + j * 4 + 12);
                a0 += (double)zr[j].x * c0.x + (double)zr[j].y * c0.y +
                      (double)zr[j].z * c0.z + (double)zr[j].w * c0.w;
                a1 += (double)zr[j+1].x * c1.x + (double)zr[j+1].y * c1.y +
                      (double)zr[j+1].z * c1.z + (double)zr[j+1].w * c1.w;
                a2 += (double)zr[j+2].x * c2.x + (double)zr[j+2].y * c2.y +
                      (double)zr[j+2].z * c2.z + (double)zr[j+2].w * c2.w;
                a3 += (double)zr[j+3].x * c3.x + (double)zr[j+3].y * c3.y +
                      (double)zr[j+3].z * c3.z + (double)zr[j+3].w * c3.w;
            }
            double a = (a0 + a1) + (a2 + a3);
            // 3-level xor reduce within 8-lane group -> all lanes get group sum
            #pragma unroll
            for (int off = 1; off < 8; off <<= 1) a += __shfl_xor(a, off);
            double s = csq64[k] - 2.0 * a;
            if (s < bs) { bs = s; bk = k; }   // per-group k strictly increasing
        }
        // global min across groups (each lane holds its group's best)
        #pragma unroll
        for (int off = 32; off > 0; off >>= 1) {
            double os = __shfl_down(bs, off);
            int    ok2 = __shfl_down(bk, off);
            if (os < bs || (os == bs && ok2 < bk)) { bs = os; bk = ok2; }
        }
        best_k = __shfl(bk, 0);
    }

    if (lane == 0) {
        oidx[row] = (float)best_k;
        atomicAdd(&freq[best_k], 1.0f);
    }
    // gather z_q = codebook[best_k] (exact -> bitwise match)
    const float* crow = cb + (size_t)best_k * D_DIM;
    *(float4*)(zq + (size_t)row * D_DIM + lane * 4) = *(const float4*)(crow + lane * 4);
    *(float4*)(zq + (size_t)row * D_DIM + 256 + lane * 4) = *(const float4*)(crow + 256 + lane * 4);
}

// ================= fallback path (R2-passing f32 pipeline) =================
__global__ __launch_bounds__(256) void csq_kernel(const float* __restrict__ cb,
                                                  float* __restrict__ csq32,
                                                  double* __restrict__ csq64,
                                                  float* __restrict__ freq,
                                                  int K) {
    int tid = threadIdx.x;
    int gt = blockIdx.x * 256 + tid;
    if (gt < K) freq[gt] = 0.0f;
    int wave = tid >> 6, lane = tid & 63;
    int k = blockIdx.x * 4 + wave;
    if (k >= K) return;
    const float* row = cb + (size_t)k * D_DIM;
    float4 v0 = *(const float4*)(row + lane * 4);
    float4 v1 = *(const float4*)(row + 256 + lane * 4);
    double s = (double)v0.x * v0.x + (double)v0.y * v0.y +
               (double)v0.z * v0.z + (double)v0.w * v0.w +
               (double)v1.x * v1.x + (double)v1.y * v1.y +
               (double)v1.z * v1.z + (double)v1.w * v1.w;
    #pragma unroll
    for (int off = 32; off > 0; off >>= 1) s += __shfl_down(s, off);
    if (lane == 0) { csq64[k] = s; csq32[k] = (float)s; }
}

__device__ __forceinline__ void top4_insert(float (&v)[4], int (&ki)[4], float s, int k) {
    if (s < v[3]) {
        v[3] = s; ki[3] = k;
        if (v[3] < v[2]) {
            float t = v[3]; v[3] = v[2]; v[2] = t; int u = ki[3]; ki[3] = ki[2]; ki[2] = u;
            if (v[2] < v[1]) {
                t = v[2]; v[2] = v[1]; v[1] = t; u = ki[2]; ki[2] = ki[1]; ki[1] = u;
                if (v[1] < v[0]) {
                    t = v[1]; v[1] = v[0]; v[0] = t; u = ki[1]; ki[1] = ki[0]; ki[0] = u;
                }
            }
        }
    }
}

#define BM 64
#define BK 128
#define BD 32
#define ZS_STRIDE (BM + 4)
#define CS_STRIDE (BK + 4)

__global__ __launch_bounds__(256) void pass1_kernel(const float* __restrict__ z,
                                                    const float* __restrict__ cb,
                                                    const float* __restrict__ csq32,
                                                    float* __restrict__ cand_v,
                                                    int* __restrict__ cand_i,
                                                    int K) {
    __shared__ float zs[BD][ZS_STRIDE];
    __shared__ float cs[BD][CS_STRIDE];
    __shared__ float mvv[BM][64];
    __shared__ int   mii[BM][64];
    const int tid = threadIdx.x;
    const int rg = tid & 15;
    const int cg = tid >> 4;
    const int row0 = blockIdx.x * BM;
    float tv[4][4]; int tk[4][4];
    #pragma unroll
    for (int r = 0; r < 4; ++r)
        #pragma unroll
        for (int m = 0; m < 4; ++m) { tv[r][m] = FLT_MAX; tk[r][m] = 0x7fffffff; }
    for (int kt = 0; kt < K; kt += BK) {
        float acc[4][8];
        #pragma unroll
        for (int r = 0; r < 4; ++r)
            #pragma unroll
            for (int cc = 0; cc < 8; ++cc) acc[r][cc] = 0.0f;
        for (int dt = 0; dt < D_DIM; dt += BD) {
            __syncthreads();
            #pragma unroll
            for (int i = 0; i < 2; ++i) {
                int lin = tid + i * 256;
                int zr = lin >> 3, dg = lin & 7;
                float4 v = *(const float4*)(z + (size_t)(row0 + zr) * D_DIM + dt + dg * 4);
                zs[dg * 4 + 0][zr] = v.x; zs[dg * 4 + 1][zr] = v.y;
                zs[dg * 4 + 2][zr] = v.z; zs[dg * 4 + 3][zr] = v.w;
            }
            #pragma unroll
            for (int i = 0; i < 4; ++i) {
                int lin = tid + i * 256;
                int cr = lin >> 3, dg = lin & 7;
                float4 v = *(const float4*)(cb + (size_t)(kt + cr) * D_DIM + dt + dg * 4);
                cs[dg * 4 + 0][cr] = v.x; cs[dg * 4 + 1][cr] = v.y;
                cs[dg * 4 + 2][cr] = v.z; cs[dg * 4 + 3][cr] = v.w;
            }
            __syncthreads();
            #pragma unroll
            for (int d = 0; d < BD; ++d) {
                float4 a = *(const float4*)&zs[d][rg * 4];
                float4 b0 = *(const float4*)&cs[d][cg * 8];
                float4 b1 = *(const float4*)&cs[d][cg * 8 + 4];
                float av[4] = {a.x, a.y, a.z, a.w};
                float bv[8] = {b0.x, b0.y, b0.z, b0.w, b1.x, b1.y, b1.z, b1.w};
                #pragma unroll
                for (int r = 0; r < 4; ++r)
                    #pragma unroll
                    for (int cc = 0; cc < 8; ++cc)
                        acc[r][cc] = fmaf(av[r], bv[cc], acc[r][cc]);
            }
        }
        #pragma unroll
        for (int cc = 0; cc < 8; ++cc) {
            int k = kt + cg * 8 + cc;
            float cq = csq32[k];
            #pragma unroll
            for (int r = 0; r < 4; ++r) {
                float s = fmaf(-2.0f, acc[r][cc], cq);
                top4_insert(tv[r], tk[r], s, k);
            }
        }
    }
    __syncthreads();
    #pragma unroll
    for (int r = 0; r < 4; ++r)
        #pragma unroll
        for (int m = 0; m < 4; ++m) {
            mvv[rg * 4 + r][cg * 4 + m] = tv[r][m];
            mii[rg * 4 + r][cg * 4 + m] = tk[r][m];
        }
    __syncthreads();
    if (tid < BM) {
        int row = tid;
        float bv[4] = {FLT_MAX, FLT_MAX, FLT_MAX, FLT_MAX};
        int   bk[4] = {0x7fffffff, 0x7fffffff, 0x7fffffff, 0x7fffffff};
        for (int j = 0; j < 64; ++j) top4_insert(bv, bk, mvv[row][j], mii[row][j]);
        #pragma unroll
        for (int m = 0; m < 4; ++m) {
            cand_v[(size_t)(row0 + row) * 4 + m] = bv[m];
            cand_i[(size_t)(row0 + row) * 4 + m] = bk[m];
        }
    }
}

__global__ __launch_bounds__(256) void pass2_kernel(const float* __restrict__ z,
                                                    const float* __restrict__ cb,
                                                    const double* __restrict__ csq64,
                                                    const float* __restrict__ cand_v,
                                                    const int* __restrict__ cand_i,
                                                    float* __restrict__ zq,
                                                    float* __restrict__ oidx,
                                                    float* __restrict__ freq,
                                                    int N, int K) {
    int lane = threadIdx.x & 63;
    int row = blockIdx.x * 4 + (threadIdx.x >> 6);
    if (row >= N) return;
    const float* zrow = z + (size_t)row * D_DIM;
    float4 z0 = *(const float4*)(zrow + lane * 4);
    float4 z1 = *(const float4*)(zrow + 256 + lane * 4);
    float cv0 = cand_v[(size_t)row * 4 + 0];
    float cv3 = cand_v[(size_t)row * 4 + 3];
    int ci[4];
    bool ok = (cv3 - cv0 >= 0.1f);
    #pragma unroll
    for (int m = 0; m < 4; ++m) {
        ci[m] = cand_i[(size_t)row * 4 + m];
        if (ci[m] < 0 || ci[m] >= K) ok = false;
    }
    double best_s = DBL_MAX;
    int best_k = 0;
    if (ok) {
        #pragma unroll
        for (int m = 0; m < 4; ++m) {
            int k = ci[m];
            const float* crow = cb + (size_t)k * D_DIM;
            float4 c0 = *(const float4*)(crow + lane * 4);
            float4 c1 = *(const float4*)(crow + 256 + lane * 4);
            double a = (double)z0.x * c0.x + (double)z0.y * c0.y +
                       (double)z0.z * c0.z + (double)z0.w * c0.w +
                       (double)z1.x * c1.x + (double)z1.y * c1.y +
                       (double)z1.z * c1.z + (double)z1.w * c1.w;
            #pragma unroll
            for (int off = 32; off > 0; off >>= 1) a += __shfl_down(a, off);
            if (lane == 0) {
                double s = csq64[k] - 2.0 * a;
                if (s < best_s || (s == best_s && k < best_k)) { best_s = s; best_k = k; }
            }
        }
    } else {
        for (int k = 0; k < K; ++k) {
            const float* crow = cb + (size_t)k * D_DIM;
            float4 c0 = *(const float4*)(crow + lane * 4);
            float4 c1 = *(const float4*)(crow + 256 + lane * 4);
            double a = (double)z0.x * c0.x + (double)z0.y * c0.y +
                       (double)z0.z * c0.z + (double)z0.w * c0.w +
                       (double)z1.x * c1.x + (double)z1.y * c1.y +
                       (double)z1.z * c1.z + (double)z1.w * c1.w;
            #pragma unroll
            for (int off = 32; off > 0; off >>= 1) a += __shfl_down(a, off);
            if (lane == 0) {
                double s = csq64[k] - 2.0 * a;
                if (s < best_s) { best_s = s; best_k = k; }
            }
        }
    }
    best_k = __shfl(best_k, 0);
    if (lane == 0) {
        oidx[row] = (float)best_k;
        atomicAdd(&freq[best_k], 1.0f);
    }
    const float* crow = cb + (size_t)best_k * D_DIM;
    *(float4*)(zq + (size_t)row * D_DIM + lane * 4) = *(const float4*)(crow + lane * 4);
    *(float4*)(zq + (size_t)row * D_DIM + 256 + lane * 4) = *(const float4*)(crow + 256 + lane * 4);
}

// ================= launcher ================================================
extern "C" void kernel_launch(void* const* d_in, const int* in_sizes, int n_in,
                              void* d_out, int out_size, void* d_ws, size_t ws_size,
                              hipStream_t stream) {
    const float* z  = (const float*)d_in[0];
    const float* cb = (const float*)d_in[1];
    const int N = in_sizes[0] / D_DIM;   // 32768
    const int K = in_sizes[1] / D_DIM;   // 4096

    float* zq   = (float*)d_out;
    float* oidx = zq + (size_t)N * D_DIM;
    float* freq = oidx + N;

    char* ws = (char*)d_ws;
    size_t o = 0;
    ushort_t* z_hi  = (ushort_t*)(ws + o); o += (size_t)N * D_DIM * 2;
    ushort_t* z_lo  = (ushort_t*)(ws + o); o += (size_t)N * D_DIM * 2;
    ushort_t* cbh   = (ushort_t*)(ws + o); o += (size_t)K * D_DIM * 2;
    ushort_t* cbl   = (ushort_t*)(ws + o); o += (size_t)K * D_DIM * 2;
    o = (o + 255) & ~(size_t)255;
    float*  csq32   = (float*)(ws + o);    o += (size_t)K * sizeof(float);
    o = (o + 255) & ~(size_t)255;
    double* csq64   = (double*)(ws + o);   o += (size_t)K * sizeof(double);
    o = (o + 255) & ~(size_t)255;
    float* cm_v0    = (float*)(ws + o);    o += (size_t)N * 2 * sizeof(float);
    float* cm_w     = (float*)(ws + o);    o += (size_t)N * 2 * sizeof(float);
    int*   cm_cnt   = (int*)(ws + o);      o += (size_t)N * 2 * sizeof(int);
    float* cand_vv  = (float*)(ws + o);    o += (size_t)N * 2 * 8 * sizeof(float);
    int*   cand_kk  = (int*)(ws + o);      o += (size_t)N * 2 * 8 * sizeof(int);
    size_t needed = o;

    if (ws_size >= needed && (N % 128) == 0 && (K % 256) == 0) {
        long total8 = (long)N * D_DIM / 8;
        hipLaunchKernelGGL(split_z_kernel, dim3((unsigned)((total8 + 255) / 256)), dim3(256),
                           0, stream, z, z_hi, z_lo, total8);
        hipLaunchKernelGGL(split_cb_kernel, dim3(K / 4), dim3(256), 0, stream,
                           cb, cbh, cbl, csq32, csq64, freq, K);
        hipLaunchKernelGGL(pass1_mfma_kernel, dim3(N / 128, 2), dim3(256), 65536, stream,
                           z_hi, z_lo, cbh, cbl, csq32,
                           cm_v0, cm_w, cm_cnt, cand_vv, cand_kk, K);
        hipLaunchKernelGGL(pass2_new_kernel, dim3(N / 4), dim3(256), 0, stream,
                           z, cb, csq64, cm_v0, cm_w, cm_cnt, cand_vv, cand_kk,
                           zq, oidx, freq, N, K);
    } else {
        // R2-passing f32 fallback (small ws footprint)
        size_t o2 = 0;
        float*  f_csq32 = (float*)(ws + o2);  o2 += (size_t)K * sizeof(float);
        o2 = (o2 + 255) & ~(size_t)255;
        double* f_csq64 = (double*)(ws + o2); o2 += (size_t)K * sizeof(double);
        o2 = (o2 + 255) & ~(size_t)255;
        float*  cand_v  = (float*)(ws + o2);  o2 += (size_t)N * 4 * sizeof(float);
        int*    cand_i  = (int*)(ws + o2);
        hipLaunchKernelGGL(csq_kernel, dim3((K + 3) / 4), dim3(256), 0, stream,
                           cb, f_csq32, f_csq64, freq, K);
        hipLaunchKernelGGL(pass1_kernel, dim3(N / BM), dim3(256), 0, stream,
                           z, cb, f_csq32, cand_v, cand_i, K);
        hipLaunchKernelGGL(pass2_kernel, dim3(N / 4), dim3(256), 0, stream,
                           z, cb, f_csq64, cand_v, cand_i, zq, oidx, freq, N, K);
    }
}

// Round 6
// 786.900 us; speedup vs baseline: 4.0176x; 2.0165x over previous
//
#include <hip/hip_runtime.h>
#include <float.h>
#include <stdint.h>

#define D_DIM 512
#define MARGIN 0.05f  // = 2*e with e=0.025 >> true approx-score error bound (~5e-3)

typedef unsigned short ushort_t;
typedef unsigned int u32;
typedef __attribute__((ext_vector_type(8))) short short8v;     // 8 bf16 (4 VGPRs)
typedef __attribute__((ext_vector_type(8))) unsigned short ushort8v;
typedef __attribute__((ext_vector_type(4))) float f32x4;

__device__ __forceinline__ ushort_t f32_bf16_rne(float x) {
    u32 u = __float_as_uint(x);
    u32 r = (u + 0x7fffu + ((u >> 16) & 1u)) >> 16;
    return (ushort_t)r;
}
__device__ __forceinline__ float bf16_f32(ushort_t h) {
    return __uint_as_float(((u32)h) << 16);
}
__device__ __forceinline__ void gload_lds16(const void* g, void* l) {
    __builtin_amdgcn_global_load_lds(
        (const __attribute__((address_space(1))) u32*)(g),
        (__attribute__((address_space(3))) u32*)(l), 16, 0, 0);
}

// ============ prep: split z into bf16 hi/lo ================================
__global__ __launch_bounds__(256) void split_z_kernel(const float* __restrict__ z,
                                                      ushort_t* __restrict__ z_hi,
                                                      ushort_t* __restrict__ z_lo,
                                                      long total8) {
    long i = (long)blockIdx.x * 256 + threadIdx.x;
    if (i >= total8) return;
    const float4* p = (const float4*)(z + i * 8);
    float4 a = p[0], b = p[1];
    float x[8] = {a.x, a.y, a.z, a.w, b.x, b.y, b.z, b.w};
    ushort8v h, lo;
    #pragma unroll
    for (int j = 0; j < 8; ++j) {
        ushort_t hh = f32_bf16_rne(x[j]);
        h[j] = hh;
        lo[j] = f32_bf16_rne(x[j] - bf16_f32(hh));
    }
    *(ushort8v*)(z_hi + i * 8) = h;
    *(ushort8v*)(z_lo + i * 8) = lo;
}

// ============ prep: split codebook + norms (f32/f64) + zero freq ===========
__global__ __launch_bounds__(256) void split_cb_kernel(const float* __restrict__ cb,
                                                       ushort_t* __restrict__ cb_hi,
                                                       ushort_t* __restrict__ cb_lo,
                                                       float* __restrict__ csq32,
                                                       double* __restrict__ csq64,
                                                       float* __restrict__ freq,
                                                       int K) {
    int tid = threadIdx.x;
    int gt = blockIdx.x * 256 + tid;
    if (gt < K) freq[gt] = 0.0f;

    int wv = tid >> 6, lane = tid & 63;
    int k = blockIdx.x * 4 + wv;
    if (k >= K) return;
    const float* row = cb + (size_t)k * D_DIM;
    float4 a = *(const float4*)(row + lane * 8);
    float4 b = *(const float4*)(row + lane * 8 + 4);
    float x[8] = {a.x, a.y, a.z, a.w, b.x, b.y, b.z, b.w};
    ushort8v h, lo;
    double s = 0.0;
    #pragma unroll
    for (int j = 0; j < 8; ++j) {
        s += (double)x[j] * x[j];
        ushort_t hh = f32_bf16_rne(x[j]);
        h[j] = hh;
        lo[j] = f32_bf16_rne(x[j] - bf16_f32(hh));
    }
    *(ushort8v*)(cb_hi + (size_t)k * D_DIM + lane * 8) = h;
    *(ushort8v*)(cb_lo + (size_t)k * D_DIM + lane * 8) = lo;
    #pragma unroll
    for (int off = 32; off > 0; off >>= 1) s += __shfl_down(s, off);
    if (lane == 0) { csq64[k] = s; csq32[k] = (float)s; }
}

// ============ pass 1: split-bf16 MFMA GEMM + per-(row,half) candidates =====
// Grid (N/128, 2): blockIdx.y = code half (16 code tiles each), K=4096 fixed.
// Emits per (row,half): v0, cnt, candidates (<=8) AND a 32-bit suspect-slot
// mask (slots whose top-2 second-best lies within MARGIN of v0) so pass2 can
// rescan only ~64 codes instead of full K on coverage failure.
__global__ __launch_bounds__(256, 2) void pass1_mfma_kernel(
        const ushort_t* __restrict__ z_hi, const ushort_t* __restrict__ z_lo,
        const ushort_t* __restrict__ cb_hi, const ushort_t* __restrict__ cb_lo,
        const float* __restrict__ csq32,
        float* __restrict__ cm_v0, int* __restrict__ cm_cnt,
        u32* __restrict__ cm_mask,
        float* __restrict__ cand_v, int* __restrict__ cand_k, int K) {
    extern __shared__ char smem[];
    const int tid = threadIdx.x;
    const int wid = tid >> 6;
    const int lane = tid & 63;
    const int wm = wid >> 1, wn = wid & 1;
    const int c = lane & 15, g = lane >> 4;
    const int row0 = blockIdx.x * 128;
    const int half = blockIdx.y;
    const int ct0 = half * 16;

    f32x4 acc[4][4];
    float tv0[16], tv1[16]; int tk0[16], tk1[16];
    #pragma unroll
    for (int i = 0; i < 16; ++i) { tv0[i] = FLT_MAX; tv1[i] = FLT_MAX; tk0[i] = 0; tk1[i] = 0; }

    auto STAGE = [&](int buf, int ct_, int t_) {
        int seg = t_ >> 3;                 // 0: hi*hi, 1: hi*lo, 2: lo*hi
        int dtt = (t_ & 7) << 6;           // d-offset within segment
        const ushort_t* As = (seg == 2) ? z_lo : z_hi;
        const ushort_t* Bs = (seg == 1) ? cb_lo : cb_hi;
        int code0_ = ct_ << 7;
        #pragma unroll
        for (int r = 0; r < 4; ++r) {
            int s = r * 256 + tid;         // 16B slot id 0..1023
            int rw = s >> 3, p = s & 7;    // row 0..127, slot-in-row 0..7
            int dswz = dtt + ((p ^ (rw & 7)) << 3);   // pre-swizzled source
            gload_lds16(As + (size_t)(row0 + rw) * D_DIM + dswz,
                        smem + buf * 16384 + r * 4096 + wid * 1024);
            gload_lds16(Bs + (size_t)(code0_ + rw) * D_DIM + dswz,
                        smem + 32768 + buf * 16384 + r * 4096 + wid * 1024);
        }
    };

    auto COMPUTE = [&](int buf) {
        const char* Ab = smem + buf * 16384;
        const char* Bb = smem + 32768 + buf * 16384;
        #pragma unroll
        for (int ks = 0; ks < 2; ++ks) {
            int q = ks * 4 + g;            // logical 16B k-slot
            short8v a[4], b[4];
            #pragma unroll
            for (int fm = 0; fm < 4; ++fm) {
                int rl = wm * 64 + fm * 16 + c;
                a[fm] = *(const short8v*)(Ab + rl * 128 + ((q ^ (rl & 7)) << 4));
            }
            #pragma unroll
            for (int fn = 0; fn < 4; ++fn) {
                int cl = wn * 64 + fn * 16 + c;
                b[fn] = *(const short8v*)(Bb + cl * 128 + ((q ^ (cl & 7)) << 4));
            }
            #pragma unroll
            for (int fm = 0; fm < 4; ++fm)
                #pragma unroll
                for (int fn = 0; fn < 4; ++fn)
                    acc[fm][fn] = __builtin_amdgcn_mfma_f32_16x16x32_bf16(
                        a[fm], b[fn], acc[fm][fn], 0, 0, 0);
        }
    };

    STAGE(0, ct0, 0);
    for (int ci = 0; ci < 16; ++ci) {
        int ct = ct0 + ci;
        f32x4 zz = {0.f, 0.f, 0.f, 0.f};
        #pragma unroll
        for (int fm = 0; fm < 4; ++fm)
            #pragma unroll
            for (int fn = 0; fn < 4; ++fn) acc[fm][fn] = zz;

        for (int t = 0; t < 24; ++t) {
            __syncthreads();               // stage(t) complete (vmcnt0 + barrier)
            if (t < 23)       STAGE((t + 1) & 1, ct, t + 1);
            else if (ci < 15) STAGE(0, ct + 1, 0);   // 24 even -> next ct starts buf0
            COMPUTE(t & 1);
        }

        // epilogue: scores + per-(thread,row) top-2 (registers only)
        int code0 = ct << 7;
        float cq[4];
        #pragma unroll
        for (int fn = 0; fn < 4; ++fn) cq[fn] = csq32[code0 + wn * 64 + fn * 16 + c];
        #pragma unroll
        for (int fm = 0; fm < 4; ++fm)
            #pragma unroll
            for (int fn = 0; fn < 4; ++fn) {
                int code = code0 + wn * 64 + fn * 16 + c;
                #pragma unroll
                for (int rg = 0; rg < 4; ++rg) {
                    float sv = fmaf(-2.0f, acc[fm][fn][rg], cq[fn]);
                    int rp = fm * 4 + rg;
                    if (sv < tv1[rp]) {
                        if (sv < tv0[rp]) {
                            tv1[rp] = tv0[rp]; tk1[rp] = tk0[rp];
                            tv0[rp] = sv;      tk0[rp] = code;
                        } else { tv1[rp] = sv; tk1[rp] = code; }
                    }
                }
            }
    }

    // ---- merge 64 entries/row (32 slots x top-2) for this half ----
    __syncthreads();                       // staging LDS reusable
    float* mv = (float*)smem;              // [128][64]
    int*   mi = (int*)(smem + 32768);      // [128][64]
    #pragma unroll
    for (int fm = 0; fm < 4; ++fm)
        #pragma unroll
        for (int rg = 0; rg < 4; ++rg) {
            int rl = wm * 64 + fm * 16 + g * 4 + rg;   // C row mapping
            int slot = wn * 16 + c;
            int rp = fm * 4 + rg;
            mv[rl * 64 + slot * 2]     = tv0[rp];
            mv[rl * 64 + slot * 2 + 1] = tv1[rp];
            mi[rl * 64 + slot * 2]     = tk0[rp];
            mi[rl * 64 + slot * 2 + 1] = tk1[rp];
        }
    __syncthreads();
    if (tid < 128) {
        const float* rv = mv + tid * 64;
        const int*   ri = mi + tid * 64;
        float v0 = FLT_MAX;
        for (int j = 0; j < 64; ++j) v0 = fminf(v0, rv[j]);
        float lim = v0 + MARGIN;
        u32 mask = 0;
        int cnt = 0; int ks[8]; float vs[8];
        for (int j = 0; j < 64; ++j)
            if (rv[j] <= lim) {
                if (cnt < 8) { ks[cnt] = ri[j]; vs[cnt] = rv[j]; }
                cnt++;
                if (j & 1) mask |= 1u << (j >> 1);   // slot-second in margin
            }
        int gidx = (row0 + tid) * 2 + half;
        cm_v0[gidx]  = v0;
        cm_cnt[gidx] = cnt;                // >8 => overflow (pass2 scans whole half)
        cm_mask[gidx] = mask;
        int st = cnt < 8 ? cnt : 8;
        for (int m = 0; m < st; ++m) {
            cand_v[(size_t)gidx * 8 + m] = vs[m];
            cand_k[(size_t)gidx * 8 + m] = ks[m];
        }
    }
}

// ============ pass 2: merge halves, f64 rescore (cands + suspect slots) ====
__global__ __launch_bounds__(256) void pass2_new_kernel(
        const float* __restrict__ z, const float* __restrict__ cb,
        const double* __restrict__ csq64,
        const float* __restrict__ cm_v0, const int* __restrict__ cm_cnt,
        const u32* __restrict__ cm_mask,
        const float* __restrict__ cand_v, const int* __restrict__ cand_k,
        float* __restrict__ zq, float* __restrict__ oidx, float* __restrict__ freq,
        int N, int K) {
    int lane = threadIdx.x & 63;
    int row = blockIdx.x * 4 + (threadIdx.x >> 6);
    if (row >= N) return;
    const int Khalf = K >> 1;              // 2048

    float v0a = cm_v0[row * 2], v0b = cm_v0[row * 2 + 1];
    int   na  = cm_cnt[row * 2], nb = cm_cnt[row * 2 + 1];
    u32   ma  = cm_mask[row * 2], mb = cm_mask[row * 2 + 1];
    float lim = fminf(v0a, v0b) + MARGIN;
    if (na > 8) ma = 0xffffffffu;          // overflow: rescan entire half
    if (nb > 8) mb = 0xffffffffu;

    // collect stored candidates <= global lim
    int ks[16]; int cnt = 0;
    {
        int sa = na < 8 ? na : 8;
        for (int m = 0; m < sa; ++m) {
            size_t idx = (size_t)(row * 2) * 8 + m;
            if (cand_v[idx] <= lim) ks[cnt++] = cand_k[idx];
        }
        int sb = nb < 8 ? nb : 8;
        for (int m = 0; m < sb; ++m) {
            size_t idx = (size_t)(row * 2 + 1) * 8 + m;
            if (cand_v[idx] <= lim) ks[cnt++] = cand_k[idx];
        }
    }

    int best_k;
    if (cnt == 1 && ma == 0 && mb == 0) {
        best_k = ks[0];                    // provably exact; ~97% of rows
    } else {
        const float* zrow = z + (size_t)row * D_DIM;
        double best_s = DBL_MAX; int bk = 0x7fffffff;

        // phase 1: rescore candidate list (64-lane d-split per code)
        {
            float4 z0 = *(const float4*)(zrow + lane * 4);
            float4 z1 = *(const float4*)(zrow + 256 + lane * 4);
            for (int m = 0; m < cnt; ++m) {
                int k = ks[m];
                const float* crow = cb + (size_t)k * D_DIM;
                float4 c0 = *(const float4*)(crow + lane * 4);
                float4 c1 = *(const float4*)(crow + 256 + lane * 4);
                double a = (double)z0.x * c0.x + (double)z0.y * c0.y +
                           (double)z0.z * c0.z + (double)z0.w * c0.w +
                           (double)z1.x * c1.x + (double)z1.y * c1.y +
                           (double)z1.z * c1.z + (double)z1.w * c1.w;
                #pragma unroll
                for (int off = 32; off > 0; off >>= 1) a += __shfl_down(a, off);
                if (lane == 0) {
                    double s = csq64[k] - 2.0 * a;
                    if (s < best_s || (s == best_s && k < bk)) { best_s = s; bk = k; }
                }
            }
            best_s = __shfl(best_s, 0);
            bk     = __shfl(bk, 0);
        }

        // phase 2: rescan suspect slots (64 codes each; 8 codes x 8 lanes)
        if (ma | mb) {
            const int cs = lane >> 3;      // code sub-index 0..7
            const int ds = lane & 7;       // d-chunk 0..7 (64 floats each)
            const float* zch = zrow + ds * 64;
            float4 zr[16];
            #pragma unroll
            for (int j = 0; j < 16; ++j) zr[j] = *(const float4*)(zch + j * 4);

            double bs2 = DBL_MAX; int bk2 = 0x7fffffff;
            for (int h = 0; h < 2; ++h) {
                u32 m = h ? mb : ma;
                while (m) {
                    int s = __ffs(m) - 1; m &= m - 1;
                    for (int tb = 0; tb < 8; ++tb) {
                        int t = tb * 8 + cs;                       // 0..63
                        int code = h * Khalf + ((t >> 2) << 7) + ((s >> 4) << 6)
                                 + ((t & 3) << 4) + (s & 15);
                        const float* crow = cb + (size_t)code * D_DIM + ds * 64;
                        double a0 = 0.0, a1 = 0.0, a2 = 0.0, a3 = 0.0;
                        #pragma unroll
                        for (int j = 0; j < 16; j += 4) {
                            float4 c0 = *(const float4*)(crow + j * 4);
                            float4 c1 = *(const float4*)(crow + j * 4 + 4);
                            float4 c2 = *(const float4*)(crow + j * 4 + 8);
                            float4 c3 = *(const float4*)(crow + j * 4 + 12);
                            a0 += (double)zr[j].x * c0.x + (double)zr[j].y * c0.y +
                                  (double)zr[j].z * c0.z + (double)zr[j].w * c0.w;
                            a1 += (double)zr[j+1].x * c1.x + (double)zr[j+1].y * c1.y +
                                  (double)zr[j+1].z * c1.z + (double)zr[j+1].w * c1.w;
                            a2 += (double)zr[j+2].x * c2.x + (double)zr[j+2].y * c2.y +
                                  (double)zr[j+2].z * c2.z + (double)zr[j+2].w * c2.w;
                            a3 += (double)zr[j+3].x * c3.x + (double)zr[j+3].y * c3.y +
                                  (double)zr[j+3].z * c3.z + (double)zr[j+3].w * c3.w;
                        }
                        double a = (a0 + a1) + (a2 + a3);
                        #pragma unroll
                        for (int off = 1; off < 8; off <<= 1) a += __shfl_xor(a, off);
                        double sc = csq64[code] - 2.0 * a;
                        if (sc < bs2 || (sc == bs2 && code < bk2)) { bs2 = sc; bk2 = code; }
                    }
                }
            }
            #pragma unroll
            for (int off = 32; off > 0; off >>= 1) {
                double os = __shfl_down(bs2, off);
                int    ok2 = __shfl_down(bk2, off);
                if (os < bs2 || (os == bs2 && ok2 < bk2)) { bs2 = os; bk2 = ok2; }
            }
            bs2 = __shfl(bs2, 0);
            bk2 = __shfl(bk2, 0);
            if (bs2 < best_s || (bs2 == best_s && bk2 < bk)) { best_s = bs2; bk = bk2; }
        }
        best_k = bk;
    }

    if (lane == 0) {
        oidx[row] = (float)best_k;
        atomicAdd(&freq[best_k], 1.0f);
    }
    // gather z_q = codebook[best_k] (exact -> bitwise match)
    const float* crow = cb + (size_t)best_k * D_DIM;
    *(float4*)(zq + (size_t)row * D_DIM + lane * 4) = *(const float4*)(crow + lane * 4);
    *(float4*)(zq + (size_t)row * D_DIM + 256 + lane * 4) = *(const float4*)(crow + 256 + lane * 4);
}

// ================= fallback path (R2-passing f32 pipeline) =================
__global__ __launch_bounds__(256) void csq_kernel(const float* __restrict__ cb,
                                                  float* __restrict__ csq32,
                                                  double* __restrict__ csq64,
                                                  float* __restrict__ freq,
                                                  int K) {
    int tid = threadIdx.x;
    int gt = blockIdx.x * 256 + tid;
    if (gt < K) freq[gt] = 0.0f;
    int wave = tid >> 6, lane = tid & 63;
    int k = blockIdx.x * 4 + wave;
    if (k >= K) return;
    const float* row = cb + (size_t)k * D_DIM;
    float4 v0 = *(const float4*)(row + lane * 4);
    float4 v1 = *(const float4*)(row + 256 + lane * 4);
    double s = (double)v0.x * v0.x + (double)v0.y * v0.y +
               (double)v0.z * v0.z + (double)v0.w * v0.w +
               (double)v1.x * v1.x + (double)v1.y * v1.y +
               (double)v1.z * v1.z + (double)v1.w * v1.w;
    #pragma unroll
    for (int off = 32; off > 0; off >>= 1) s += __shfl_down(s, off);
    if (lane == 0) { csq64[k] = s; csq32[k] = (float)s; }
}

__device__ __forceinline__ void top4_insert(float (&v)[4], int (&ki)[4], float s, int k) {
    if (s < v[3]) {
        v[3] = s; ki[3] = k;
        if (v[3] < v[2]) {
            float t = v[3]; v[3] = v[2]; v[2] = t; int u = ki[3]; ki[3] = ki[2]; ki[2] = u;
            if (v[2] < v[1]) {
                t = v[2]; v[2] = v[1]; v[1] = t; u = ki[2]; ki[2] = ki[1]; ki[1] = u;
                if (v[1] < v[0]) {
                    t = v[1]; v[1] = v[0]; v[0] = t; u = ki[1]; ki[1] = ki[0]; ki[0] = u;
                }
            }
        }
    }
}

#define BM 64
#define BK 128
#define BD 32
#define ZS_STRIDE (BM + 4)
#define CS_STRIDE (BK + 4)

__global__ __launch_bounds__(256) void pass1_kernel(const float* __restrict__ z,
                                                    const float* __restrict__ cb,
                                                    const float* __restrict__ csq32,
                                                    float* __restrict__ cand_v,
                                                    int* __restrict__ cand_i,
                                                    int K) {
    __shared__ float zs[BD][ZS_STRIDE];
    __shared__ float cs[BD][CS_STRIDE];
    __shared__ float mvv[BM][64];
    __shared__ int   mii[BM][64];
    const int tid = threadIdx.x;
    const int rg = tid & 15;
    const int cg = tid >> 4;
    const int row0 = blockIdx.x * BM;
    float tv[4][4]; int tk[4][4];
    #pragma unroll
    for (int r = 0; r < 4; ++r)
        #pragma unroll
        for (int m = 0; m < 4; ++m) { tv[r][m] = FLT_MAX; tk[r][m] = 0x7fffffff; }
    for (int kt = 0; kt < K; kt += BK) {
        float acc[4][8];
        #pragma unroll
        for (int r = 0; r < 4; ++r)
            #pragma unroll
            for (int cc = 0; cc < 8; ++cc) acc[r][cc] = 0.0f;
        for (int dt = 0; dt < D_DIM; dt += BD) {
            __syncthreads();
            #pragma unroll
            for (int i = 0; i < 2; ++i) {
                int lin = tid + i * 256;
                int zr = lin >> 3, dg = lin & 7;
                float4 v = *(const float4*)(z + (size_t)(row0 + zr) * D_DIM + dt + dg * 4);
                zs[dg * 4 + 0][zr] = v.x; zs[dg * 4 + 1][zr] = v.y;
                zs[dg * 4 + 2][zr] = v.z; zs[dg * 4 + 3][zr] = v.w;
            }
            #pragma unroll
            for (int i = 0; i < 4; ++i) {
                int lin = tid + i * 256;
                int cr = lin >> 3, dg = lin & 7;
                float4 v = *(const float4*)(cb + (size_t)(kt + cr) * D_DIM + dt + dg * 4);
                cs[dg * 4 + 0][cr] = v.x; cs[dg * 4 + 1][cr] = v.y;
                cs[dg * 4 + 2][cr] = v.z; cs[dg * 4 + 3][cr] = v.w;
            }
            __syncthreads();
            #pragma unroll
            for (int d = 0; d < BD; ++d) {
                float4 a = *(const float4*)&zs[d][rg * 4];
                float4 b0 = *(const float4*)&cs[d][cg * 8];
                float4 b1 = *(const float4*)&cs[d][cg * 8 + 4];
                float av[4] = {a.x, a.y, a.z, a.w};
                float bv[8] = {b0.x, b0.y, b0.z, b0.w, b1.x, b1.y, b1.z, b1.w};
                #pragma unroll
                for (int r = 0; r < 4; ++r)
                    #pragma unroll
                    for (int cc = 0; cc < 8; ++cc)
                        acc[r][cc] = fmaf(av[r], bv[cc], acc[r][cc]);
            }
        }
        #pragma unroll
        for (int cc = 0; cc < 8; ++cc) {
            int k = kt + cg * 8 + cc;
            float cq = csq32[k];
            #pragma unroll
            for (int r = 0; r < 4; ++r) {
                float s = fmaf(-2.0f, acc[r][cc], cq);
                top4_insert(tv[r], tk[r], s, k);
            }
        }
    }
    __syncthreads();
    #pragma unroll
    for (int r = 0; r < 4; ++r)
        #pragma unroll
        for (int m = 0; m < 4; ++m) {
            mvv[rg * 4 + r][cg * 4 + m] = tv[r][m];
            mii[rg * 4 + r][cg * 4 + m] = tk[r][m];
        }
    __syncthreads();
    if (tid < BM) {
        int row = tid;
        float bv[4] = {FLT_MAX, FLT_MAX, FLT_MAX, FLT_MAX};
        int   bk[4] = {0x7fffffff, 0x7fffffff, 0x7fffffff, 0x7fffffff};
        for (int j = 0; j < 64; ++j) top4_insert(bv, bk, mvv[row][j], mii[row][j]);
        #pragma unroll
        for (int m = 0; m < 4; ++m) {
            cand_v[(size_t)(row0 + row) * 4 + m] = bv[m];
            cand_i[(size_t)(row0 + row) * 4 + m] = bk[m];
        }
    }
}

__global__ __launch_bounds__(256) void pass2_kernel(const float* __restrict__ z,
                                                    const float* __restrict__ cb,
                                                    const double* __restrict__ csq64,
                                                    const float* __restrict__ cand_v,
                                                    const int* __restrict__ cand_i,
                                                    float* __restrict__ zq,
                                                    float* __restrict__ oidx,
                                                    float* __restrict__ freq,
                                                    int N, int K) {
    int lane = threadIdx.x & 63;
    int row = blockIdx.x * 4 + (threadIdx.x >> 6);
    if (row >= N) return;
    const float* zrow = z + (size_t)row * D_DIM;
    float4 z0 = *(const float4*)(zrow + lane * 4);
    float4 z1 = *(const float4*)(zrow + 256 + lane * 4);
    float cv0 = cand_v[(size_t)row * 4 + 0];
    float cv3 = cand_v[(size_t)row * 4 + 3];
    int ci[4];
    bool ok = (cv3 - cv0 >= 0.1f);
    #pragma unroll
    for (int m = 0; m < 4; ++m) {
        ci[m] = cand_i[(size_t)row * 4 + m];
        if (ci[m] < 0 || ci[m] >= K) ok = false;
    }
    double best_s = DBL_MAX;
    int best_k = 0;
    if (ok) {
        #pragma unroll
        for (int m = 0; m < 4; ++m) {
            int k = ci[m];
            const float* crow = cb + (size_t)k * D_DIM;
            float4 c0 = *(const float4*)(crow + lane * 4);
            float4 c1 = *(const float4*)(crow + 256 + lane * 4);
            double a = (double)z0.x * c0.x + (double)z0.y * c0.y +
                       (double)z0.z * c0.z + (double)z0.w * c0.w +
                       (double)z1.x * c1.x + (double)z1.y * c1.y +
                       (double)z1.z * c1.z + (double)z1.w * c1.w;
            #pragma unroll
            for (int off = 32; off > 0; off >>= 1) a += __shfl_down(a, off);
            if (lane == 0) {
                double s = csq64[k] - 2.0 * a;
                if (s < best_s || (s == best_s && k < best_k)) { best_s = s; best_k = k; }
            }
        }
    } else {
        for (int k = 0; k < K; ++k) {
            const float* crow = cb + (size_t)k * D_DIM;
            float4 c0 = *(const float4*)(crow + lane * 4);
            float4 c1 = *(const float4*)(crow + 256 + lane * 4);
            double a = (double)z0.x * c0.x + (double)z0.y * c0.y +
                       (double)z0.z * c0.z + (double)z0.w * c0.w +
                       (double)z1.x * c1.x + (double)z1.y * c1.y +
                       (double)z1.z * c1.z + (double)z1.w * c1.w;
            #pragma unroll
            for (int off = 32; off > 0; off >>= 1) a += __shfl_down(a, off);
            if (lane == 0) {
                double s = csq64[k] - 2.0 * a;
                if (s < best_s) { best_s = s; best_k = k; }
            }
        }
    }
    best_k = __shfl(best_k, 0);
    if (lane == 0) {
        oidx[row] = (float)best_k;
        atomicAdd(&freq[best_k], 1.0f);
    }
    const float* crow = cb + (size_t)best_k * D_DIM;
    *(float4*)(zq + (size_t)row * D_DIM + lane * 4) = *(const float4*)(crow + lane * 4);
    *(float4*)(zq + (size_t)row * D_DIM + 256 + lane * 4) = *(const float4*)(crow + 256 + lane * 4);
}

// ================= launcher ================================================
extern "C" void kernel_launch(void* const* d_in, const int* in_sizes, int n_in,
                              void* d_out, int out_size, void* d_ws, size_t ws_size,
                              hipStream_t stream) {
    const float* z  = (const float*)d_in[0];
    const float* cb = (const float*)d_in[1];
    const int N = in_sizes[0] / D_DIM;   // 32768
    const int K = in_sizes[1] / D_DIM;   // 4096

    float* zq   = (float*)d_out;
    float* oidx = zq + (size_t)N * D_DIM;
    float* freq = oidx + N;

    char* ws = (char*)d_ws;
    size_t o = 0;
    ushort_t* z_hi  = (ushort_t*)(ws + o); o += (size_t)N * D_DIM * 2;
    ushort_t* z_lo  = (ushort_t*)(ws + o); o += (size_t)N * D_DIM * 2;
    ushort_t* cbh   = (ushort_t*)(ws + o); o += (size_t)K * D_DIM * 2;
    ushort_t* cbl   = (ushort_t*)(ws + o); o += (size_t)K * D_DIM * 2;
    o = (o + 255) & ~(size_t)255;
    float*  csq32   = (float*)(ws + o);    o += (size_t)K * sizeof(float);
    o = (o + 255) & ~(size_t)255;
    double* csq64   = (double*)(ws + o);   o += (size_t)K * sizeof(double);
    o = (o + 255) & ~(size_t)255;
    float* cm_v0    = (float*)(ws + o);    o += (size_t)N * 2 * sizeof(float);
    int*   cm_cnt   = (int*)(ws + o);      o += (size_t)N * 2 * sizeof(int);
    u32*   cm_mask  = (u32*)(ws + o);      o += (size_t)N * 2 * sizeof(u32);
    float* cand_vv  = (float*)(ws + o);    o += (size_t)N * 2 * 8 * sizeof(float);
    int*   cand_kk  = (int*)(ws + o);      o += (size_t)N * 2 * 8 * sizeof(int);
    size_t needed = o;

    if (ws_size >= needed && (N % 128) == 0 && K == 4096) {
        long total8 = (long)N * D_DIM / 8;
        hipLaunchKernelGGL(split_z_kernel, dim3((unsigned)((total8 + 255) / 256)), dim3(256),
                           0, stream, z, z_hi, z_lo, total8);
        hipLaunchKernelGGL(split_cb_kernel, dim3(K / 4), dim3(256), 0, stream,
                           cb, cbh, cbl, csq32, csq64, freq, K);
        hipLaunchKernelGGL(pass1_mfma_kernel, dim3(N / 128, 2), dim3(256), 65536, stream,
                           z_hi, z_lo, cbh, cbl, csq32,
                           cm_v0, cm_cnt, cm_mask, cand_vv, cand_kk, K);
        hipLaunchKernelGGL(pass2_new_kernel, dim3(N / 4), dim3(256), 0, stream,
                           z, cb, csq64, cm_v0, cm_cnt, cm_mask, cand_vv, cand_kk,
                           zq, oidx, freq, N, K);
    } else {
        // R2-passing f32 fallback (small ws footprint)
        size_t o2 = 0;
        float*  f_csq32 = (float*)(ws + o2);  o2 += (size_t)K * sizeof(float);
        o2 = (o2 + 255) & ~(size_t)255;
        double* f_csq64 = (double*)(ws + o2); o2 += (size_t)K * sizeof(double);
        o2 = (o2 + 255) & ~(size_t)255;
        float*  cand_v  = (float*)(ws + o2);  o2 += (size_t)N * 4 * sizeof(float);
        int*    cand_i  = (int*)(ws + o2);
        hipLaunchKernelGGL(csq_kernel, dim3((K + 3) / 4), dim3(256), 0, stream,
                           cb, f_csq32, f_csq64, freq, K);
        hipLaunchKernelGGL(pass1_kernel, dim3(N / BM), dim3(256), 0, stream,
                           z, cb, f_csq32, cand_v, cand_i, K);
        hipLaunchKernelGGL(pass2_kernel, dim3(N / 4), dim3(256), 0, stream,
                           z, cb, f_csq64, cand_v, cand_i, zq, oidx, freq, N, K);
    }
}